// Round 18
// baseline (450.296 us; speedup 1.0000x reference)
//
#include <hip/hip_runtime.h>

#define ROWS 6304      // B*N = 32*197
#define MPAD 6400      // 50 * 128
#define CDIM 1024
#define QKVD 3072
#define FFD  4096
#define NSEQ 197
#define NBH  512       // B*H
#define NPREP (3072 + ROWS)   // 9376

typedef __attribute__((ext_vector_type(8))) short bf16x8;
typedef __attribute__((ext_vector_type(4))) float f32x4;
typedef __attribute__((ext_vector_type(4))) int i32x4;

// ---------- device helpers ----------
__device__ __forceinline__ float fqv(float v, float s) {
    float q = rintf(v / s);
    q = fminf(fmaxf(q, -127.0f), 127.0f);
    return q * s;
}
__device__ __forceinline__ float gelu_f(float x) {
    const float c = 0.7978845608028654f;  // sqrt(2/pi)
    float t = tanhf(c * (x + 0.044715f * x * x * x));
    return 0.5f * x * (1.0f + t);
}
__device__ __forceinline__ short bf16_of_small_int(float q) {
    return (short)(__float_as_uint(q) >> 16);  // exact for |q| <= 255 integers
}
__device__ __forceinline__ short q_bf16(float v, float s) {
    return bf16_of_small_int(fminf(fmaxf(rintf(v / s), -127.f), 127.f));
}
// block = 256 threads (4 waves)
__device__ __forceinline__ float blockReduceSum(float v, float* sred) {
    int lane = threadIdx.x & 63, w = threadIdx.x >> 6;
    #pragma unroll
    for (int o = 32; o > 0; o >>= 1) v += __shfl_down(v, o);
    __syncthreads();
    if (lane == 0) sred[w] = v;
    __syncthreads();
    return sred[0] + sred[1] + sred[2] + sred[3];
}
__device__ __forceinline__ float blockReduceMax(float v, float* sred) {
    int lane = threadIdx.x & 63, w = threadIdx.x >> 6;
    #pragma unroll
    for (int o = 32; o > 0; o >>= 1) v = fmaxf(v, __shfl_down(v, o));
    __syncthreads();
    if (lane == 0) sred[w] = v;
    __syncthreads();
    return fmaxf(fmaxf(sred[0], sred[1]), fmaxf(sred[2], sred[3]));
}
// block = 512 threads (8 waves)
__device__ __forceinline__ float blockReduceMax8(float v, float* sred) {
    int lane = threadIdx.x & 63, w = threadIdx.x >> 6;
    #pragma unroll
    for (int o = 32; o > 0; o >>= 1) v = fmaxf(v, __shfl_down(v, o));
    __syncthreads();
    if (lane == 0) sred[w] = v;
    __syncthreads();
    float m = sred[0];
    #pragma unroll
    for (int i = 1; i < 8; i++) m = fmaxf(m, sred[i]);
    return m;
}
// inline amax over a partials array (256-thread blocks), broadcast to all threads
__device__ __forceinline__ float pmax256(const float* part, int n, float* sred) {
    float m = 0.f;
    for (int i = threadIdx.x; i < n; i += 256) m = fmaxf(m, part[i]);
    return blockReduceMax(m, sred);
}
__device__ __forceinline__ float scale_v(float amv) {
    return fmaxf(amv / 127.0f, 1e-8f);
}
__device__ __forceinline__ float scale_of(const float* am) {
    return fmaxf(am[0] / 127.0f, 1e-8f);
}

// ---------- prep_a: weight absmax (blocks 0..3071) || LN1 amax (3072..9375) ----------
__global__ __launch_bounds__(256) void prep_a_kernel(
    const float* __restrict__ w0, const float* __restrict__ w1,
    const float* __restrict__ w2, const float* __restrict__ w3,
    const float* __restrict__ x, const float* __restrict__ g1,
    const float* __restrict__ b1, float* __restrict__ part) {
    __shared__ float sred[4];
    int b = blockIdx.x, tid = threadIdx.x;
    if (b < 3072) {
        const float4* p; int base, nb;
        if (b < 768)       { p = (const float4*)w0; base = b;        nb = 768;  }
        else if (b < 1024) { p = (const float4*)w1; base = b - 768;  nb = 256;  }
        else if (b < 2048) { p = (const float4*)w2; base = b - 1024; nb = 1024; }
        else               { p = (const float4*)w3; base = b - 2048; nb = 1024; }
        float m = 0.f;
        #pragma unroll
        for (int it = 0; it < 4; it++) {
            float4 v = p[(long long)it * nb * 256 + (long long)base * 256 + tid];
            m = fmaxf(m, fmaxf(fmaxf(fabsf(v.x), fabsf(v.y)), fmaxf(fabsf(v.z), fabsf(v.w))));
        }
        m = blockReduceMax(m, sred);
        if (tid == 0) part[b] = m;
    } else {
        int row = b - 3072;
        float4 v = ((const float4*)(x + (size_t)row * CDIM))[tid];
        float sum = blockReduceSum(v.x + v.y + v.z + v.w, sred);
        float mu = sum * (1.0f / CDIM);
        float dx = v.x - mu, dy = v.y - mu, dz = v.z - mu, dw = v.w - mu;
        float var = blockReduceSum(dx * dx + dy * dy + dz * dz + dw * dw, sred) * (1.0f / CDIM);
        float rstd = rsqrtf(var + 1e-6f);
        float4 gv = ((const float4*)g1)[tid], bv = ((const float4*)b1)[tid];
        float ox = dx * rstd * gv.x + bv.x;
        float oy = dy * rstd * gv.y + bv.y;
        float oz = dz * rstd * gv.z + bv.z;
        float ow = dw * rstd * gv.w + bv.w;
        float m = fmaxf(fmaxf(fabsf(ox), fabsf(oy)), fmaxf(fabsf(oz), fabsf(ow)));
        m = blockReduceMax(m, sred);
        if (tid == 0) part[b] = m;
    }
}

// one block: collapse prep_a partials into am[0..4] (sole writer, plain stores)
__global__ __launch_bounds__(256) void reduce_am5_kernel(const float* __restrict__ part,
                                                         float* __restrict__ am) {
    __shared__ float sred[4];
    float m0 = 0.f, m1 = 0.f, m2 = 0.f, m3 = 0.f, m4 = 0.f;
    for (int i = threadIdx.x; i < NPREP; i += 256) {
        float v = part[i];
        if (i < 768) m0 = fmaxf(m0, v);
        else if (i < 1024) m1 = fmaxf(m1, v);
        else if (i < 2048) m2 = fmaxf(m2, v);
        else if (i < 3072) m3 = fmaxf(m3, v);
        else m4 = fmaxf(m4, v);
    }
    m0 = blockReduceMax(m0, sred);
    m1 = blockReduceMax(m1, sred);
    m2 = blockReduceMax(m2, sred);
    m3 = blockReduceMax(m3, sred);
    m4 = blockReduceMax(m4, sred);
    if (threadIdx.x == 0) { am[0] = m0; am[1] = m1; am[2] = m2; am[3] = m3; am[4] = m4; }
}

// one block: amDst[0] = max(part[0..n))
__global__ __launch_bounds__(256) void reduce_one_kernel(const float* __restrict__ part,
                                                         int n, float* __restrict__ amDst) {
    __shared__ float sred[4];
    float m = 0.f;
    for (int i = threadIdx.x; i < n; i += 256) m = fmaxf(m, part[i]);
    m = blockReduceMax(m, sred);
    if (threadIdx.x == 0) amDst[0] = m;
}

// ---------- prep_b: weight quant || LN1 recompute-quant || xnq pad-zero ----------
// grid NPREP + 96: blocks >= NPREP zero one pad row of xnq each (replaces memset)
__global__ __launch_bounds__(256) void prep_b_kernel(
    const float* __restrict__ w0, signed char* __restrict__ d0,
    const float* __restrict__ w1, signed char* __restrict__ d1,
    const float* __restrict__ w2, signed char* __restrict__ d2,
    const float* __restrict__ w3, signed char* __restrict__ d3,
    const float* __restrict__ x, const float* __restrict__ g1,
    const float* __restrict__ b1, signed char* __restrict__ xnq,
    const float* __restrict__ am) {
    __shared__ float sred[4];
    int b = blockIdx.x, tid = threadIdx.x;
    if (b >= NPREP) {
        int row = ROWS + (b - NPREP);
        ((int*)xnq)[(size_t)row * (CDIM / 4) + tid] = 0;
        return;
    }
    if (b < 3072) {
        const float4* p; int* d; int base, nb; float s;
        if (b < 768)       { p = (const float4*)w0; d = (int*)d0; base = b;        nb = 768;  s = scale_of(am + 0); }
        else if (b < 1024) { p = (const float4*)w1; d = (int*)d1; base = b - 768;  nb = 256;  s = scale_of(am + 1); }
        else if (b < 2048) { p = (const float4*)w2; d = (int*)d2; base = b - 1024; nb = 1024; s = scale_of(am + 2); }
        else               { p = (const float4*)w3; d = (int*)d3; base = b - 2048; nb = 1024; s = scale_of(am + 3); }
        #pragma unroll
        for (int it = 0; it < 4; it++) {
            long long i = (long long)it * nb * 256 + (long long)base * 256 + tid;
            float4 v = p[i];
            int q0 = (int)fminf(fmaxf(rintf(v.x / s), -127.f), 127.f);
            int q1 = (int)fminf(fmaxf(rintf(v.y / s), -127.f), 127.f);
            int q2 = (int)fminf(fmaxf(rintf(v.z / s), -127.f), 127.f);
            int q3 = (int)fminf(fmaxf(rintf(v.w / s), -127.f), 127.f);
            d[i] = (q0 & 255) | ((q1 & 255) << 8) | ((q2 & 255) << 16) | (q3 << 24);
        }
    } else {
        int row = b - 3072;
        float4 v = ((const float4*)(x + (size_t)row * CDIM))[tid];
        float sum = blockReduceSum(v.x + v.y + v.z + v.w, sred);
        float mu = sum * (1.0f / CDIM);
        float dx = v.x - mu, dy = v.y - mu, dz = v.z - mu, dw = v.w - mu;
        float var = blockReduceSum(dx * dx + dy * dy + dz * dz + dw * dw, sred) * (1.0f / CDIM);
        float rstd = rsqrtf(var + 1e-6f);
        float4 gv = ((const float4*)g1)[tid], bv = ((const float4*)b1)[tid];
        float ox = dx * rstd * gv.x + bv.x;
        float oy = dy * rstd * gv.y + bv.y;
        float oz = dz * rstd * gv.z + bv.z;
        float ow = dw * rstd * gv.w + bv.w;
        float s = scale_of(am + 4);
        int q0 = (int)fminf(fmaxf(rintf(ox / s), -127.f), 127.f);
        int q1 = (int)fminf(fmaxf(rintf(oy / s), -127.f), 127.f);
        int q2 = (int)fminf(fmaxf(rintf(oz / s), -127.f), 127.f);
        int q3 = (int)fminf(fmaxf(rintf(ow / s), -127.f), 127.f);
        ((int*)xnq)[(size_t)row * (CDIM / 4) + tid] =
            (q0 & 255) | ((q1 & 255) << 8) | ((q2 & 255) << 16) | (q3 << 24);
    }
}

// ---------- LayerNorm (LN2): MODE 0 partial amax; MODE 1 recompute-quant ----------
template <int MODE>
__global__ __launch_bounds__(256) void ln_kernel(
    const float* __restrict__ x, const float* __restrict__ g,
    const float* __restrict__ bb, signed char* __restrict__ dst,
    const float* __restrict__ partIn, int nIn,
    const float* __restrict__ amQ, float* __restrict__ part) {
    __shared__ float sred[4];
    int row = blockIdx.x;
    int t = threadIdx.x;
    float sIn = scale_v(pmax256(partIn, nIn, sred));
    float4 v = ((const float4*)(x + (size_t)row * CDIM))[t];
    v.x = fqv(v.x, sIn); v.y = fqv(v.y, sIn); v.z = fqv(v.z, sIn); v.w = fqv(v.w, sIn);
    float sum = blockReduceSum(v.x + v.y + v.z + v.w, sred);
    float mu = sum * (1.0f / CDIM);
    float dx = v.x - mu, dy = v.y - mu, dz = v.z - mu, dw = v.w - mu;
    float var = blockReduceSum(dx * dx + dy * dy + dz * dz + dw * dw, sred) * (1.0f / CDIM);
    float rstd = rsqrtf(var + 1e-6f);
    float4 gv = ((const float4*)g)[t], bv = ((const float4*)bb)[t];
    float ox = dx * rstd * gv.x + bv.x;
    float oy = dy * rstd * gv.y + bv.y;
    float oz = dz * rstd * gv.z + bv.z;
    float ow = dw * rstd * gv.w + bv.w;
    if (MODE == 0) {
        float m = fmaxf(fmaxf(fabsf(ox), fabsf(oy)), fmaxf(fabsf(oz), fabsf(ow)));
        m = blockReduceMax(m, sred);
        if (t == 0) part[row] = m;
    } else {
        float s = scale_of(amQ);
        int q0 = (int)fminf(fmaxf(rintf(ox / s), -127.f), 127.f);
        int q1 = (int)fminf(fmaxf(rintf(oy / s), -127.f), 127.f);
        int q2 = (int)fminf(fmaxf(rintf(oz / s), -127.f), 127.f);
        int q3 = (int)fminf(fmaxf(rintf(ow / s), -127.f), 127.f);
        ((int*)dst)[(size_t)row * (CDIM / 4) + t] =
            (q0 & 255) | ((q1 & 255) << 8) | ((q2 & 255) << 16) | (q3 << 24);
    }
}

// final fq: s from partials
__global__ __launch_bounds__(256) void fq_inplace_kernel(float* __restrict__ buf, long long n4,
                                                         const float* __restrict__ part, int np) {
    __shared__ float sred[4];
    float s = scale_v(pmax256(part, np, sred));
    float4* b4 = (float4*)buf;
    long long stride = (long long)gridDim.x * blockDim.x;
    for (long long i = (long long)blockIdx.x * blockDim.x + threadIdx.x; i < n4; i += stride) {
        float4 v = b4[i];
        v.x = fqv(v.x, s); v.y = fqv(v.y, s); v.z = fqv(v.z, s); v.w = fqv(v.w, s);
        b4[i] = v;
    }
}

// buf[i] = FQ?(xin[i], sX) + fq(buf[i], s); scales from partials; partOut[bid] = block max
__global__ __launch_bounds__(256) void addfq_kernel(const float* __restrict__ xin,
                                                    const float* __restrict__ partX, int nX,
                                                    float* __restrict__ buf, long long n4,
                                                    const float* __restrict__ partAm, int nAm,
                                                    float* __restrict__ partOut) {
    __shared__ float sred[4];
    float s = scale_v(pmax256(partAm, nAm, sred));
    float sx = partX ? scale_v(pmax256(partX, nX, sred)) : 0.f;
    const float4* x4 = (const float4*)xin;
    float4* b4 = (float4*)buf;
    float m = 0.f;
    long long stride = (long long)gridDim.x * blockDim.x;
    for (long long i = (long long)blockIdx.x * blockDim.x + threadIdx.x; i < n4; i += stride) {
        float4 v = x4[i];
        if (partX) { v.x = fqv(v.x, sx); v.y = fqv(v.y, sx); v.z = fqv(v.z, sx); v.w = fqv(v.w, sx); }
        float4 u = b4[i];
        u.x = v.x + fqv(u.x, s);
        u.y = v.y + fqv(u.y, s);
        u.z = v.z + fqv(u.z, s);
        u.w = v.w + fqv(u.w, s);
        b4[i] = u;
        m = fmaxf(m, fmaxf(fmaxf(fabsf(u.x), fabsf(u.y)), fmaxf(fabsf(u.z), fabsf(u.w))));
    }
    m = blockReduceMax(m, sred);
    if (threadIdx.x == 0) partOut[blockIdx.x] = m;
}

// quantize to i8 levels, scale from partials, zeros for i>=n
__global__ __launch_bounds__(256) void quant_i8_kernel(const float* __restrict__ src,
                                                       signed char* __restrict__ dst,
                                                       long long n4, long long npad4,
                                                       const float* __restrict__ part, int np) {
    __shared__ float sred[4];
    float s = scale_v(pmax256(part, np, sred));
    long long stride = (long long)gridDim.x * blockDim.x;
    for (long long i = (long long)blockIdx.x * blockDim.x + threadIdx.x; i < npad4; i += stride) {
        float4 v = make_float4(0.f, 0.f, 0.f, 0.f);
        if (i < n4) v = ((const float4*)src)[i];
        int q0 = (int)fminf(fmaxf(rintf(v.x / s), -127.f), 127.f);
        int q1 = (int)fminf(fmaxf(rintf(v.y / s), -127.f), 127.f);
        int q2 = (int)fminf(fmaxf(rintf(v.z / s), -127.f), 127.f);
        int q3 = (int)fminf(fmaxf(rintf(v.w / s), -127.f), 127.f);
        ((int*)dst)[i] = (q0 & 255) | ((q1 & 255) << 8) | ((q2 & 255) << 16) | (q3 << 24);
    }
}

// ---------- qv: blocks [0,2048) quantize Q,K cols -> bf16 levels; [2048,2560) V-transpose ----------
__global__ __launch_bounds__(256) void qv_kernel(const float* __restrict__ qkvF,
                                                 short* __restrict__ qkvq,
                                                 short* __restrict__ vtq,
                                                 const float* __restrict__ part5, int np5) {
    __shared__ short T[NSEQ * 65];
    __shared__ float sred[4];
    float s = scale_v(pmax256(part5, np5, sred));
    int b = blockIdx.x, tid = threadIdx.x;
    if (b < 2048) {
        const long long n4 = (long long)ROWS * 512;
        for (long long i = (long long)b * 256 + tid; i < n4; i += (long long)2048 * 256) {
            long long row = i >> 9;
            int c4 = (int)(i & 511);
            float4 v = ((const float4*)(qkvF + row * QKVD))[c4];
            short4 o;
            o.x = q_bf16(v.x, s); o.y = q_bf16(v.y, s);
            o.z = q_bf16(v.z, s); o.w = q_bf16(v.w, s);
            ((short4*)(qkvq + row * QKVD))[c4] = o;
        }
    } else {
        int z = b - 2048, bb = z >> 4, hh = z & 15;
        const float* vb = qkvF + (size_t)bb * NSEQ * QKVD + 2048 + hh * 64;
        for (int c = tid; c < NSEQ * 16; c += 256) {
            int m = c >> 4, p = c & 15;
            float4 v = ((const float4*)(vb + (size_t)m * QKVD))[p];
            T[m * 65 + p * 4 + 0] = q_bf16(v.x, s);
            T[m * 65 + p * 4 + 1] = q_bf16(v.y, s);
            T[m * 65 + p * 4 + 2] = q_bf16(v.z, s);
            T[m * 65 + p * 4 + 3] = q_bf16(v.w, s);
        }
        __syncthreads();
        short* obase = vtq + (size_t)z * 64 * 256;
        for (int c = tid; c < 64 * 32; c += 256) {
            int d = c >> 5, sl = c & 31;
            int sp = sl ^ (d & 7);
            bf16x8 o;
            #pragma unroll
            for (int jj = 0; jj < 8; jj++) {
                int m = sl * 8 + jj;
                o[jj] = (m < NSEQ) ? T[m * 65 + d] : (short)0;
            }
            *(bf16x8*)&obase[d * 256 + sp * 8] = o;
        }
    }
}

#define GLL(gp, lp) __builtin_amdgcn_global_load_lds( \
    (const __attribute__((address_space(1))) void*)(gp), \
    (__attribute__((address_space(3))) void*)(lp), 16, 0, 0)

// ---------- attention pass 1: amax(S) only, s5 from partials ----------
__global__ __launch_bounds__(256, 2) void attn_amax_kernel(
    const short* __restrict__ qkvq,
    const float* __restrict__ part5, int np5, float* __restrict__ part) {
    __shared__ __align__(16) short Qs[256 * 32];
    __shared__ __align__(16) short Ks[64 * 32];
    __shared__ float sred[4];
    const int tid = threadIdx.x, lane = tid & 63, wave = tid >> 6;
    const int z = blockIdx.z, b = z >> 4, hh = z & 15;
    const int n0 = blockIdx.x * 64;
    const float s5 = scale_v(pmax256(part5, np5, sred));
    const float sc = s5 * s5 * 0.125f;
    const short* qbase = qkvq + (size_t)b * NSEQ * QKVD + hh * 64;
    const short* kbase = qbase + 1024;

    f32x4 acc[4][4] = {};
    const int piece = (tid & 3) * 8;
    const short* srcA[4];
    #pragma unroll
    for (int i = 0; i < 4; i++) {
        int row = i * 64 + (tid >> 2);
        srcA[i] = qbase + (size_t)min(row, NSEQ - 1) * QKVD + piece;
    }
    const short* srcB = kbase + (size_t)min(n0 + (tid >> 2), NSEQ - 1) * QKVD + piece;
    const int lr = lane & 15;
    const int koff = (lane >> 4) * 8;

    for (int k0 = 0; k0 < 64; k0 += 32) {
        __syncthreads();
        #pragma unroll
        for (int i = 0; i < 4; i++) GLL(srcA[i] + k0, Qs + i * 2048 + wave * 512);
        GLL(srcB + k0, Ks + wave * 512);
        __syncthreads();

        bf16x8 a[4], bfr[4];
        #pragma unroll
        for (int i = 0; i < 4; i++)
            a[i] = *(const bf16x8*)&Qs[(wave * 64 + i * 16 + lr) * 32 + koff];
        #pragma unroll
        for (int j = 0; j < 4; j++)
            bfr[j] = *(const bf16x8*)&Ks[(j * 16 + lr) * 32 + koff];
        #pragma unroll
        for (int i = 0; i < 4; i++)
            #pragma unroll
            for (int j = 0; j < 4; j++)
                acc[i][j] = __builtin_amdgcn_mfma_f32_16x16x32_bf16(a[i], bfr[j], acc[i][j], 0, 0, 0);
    }

    const int cr = (lane >> 4) * 4;
    const int cc = lane & 15;
    float mloc = 0.f;
    #pragma unroll
    for (int i = 0; i < 4; i++) {
        #pragma unroll
        for (int j = 0; j < 4; j++) {
            int gn = n0 + j * 16 + cc;
            #pragma unroll
            for (int r = 0; r < 4; r++) {
                int gm = wave * 64 + i * 16 + cr + r;
                if (gm < NSEQ && gn < NSEQ)
                    mloc = fmaxf(mloc, fabsf(acc[i][j][r] * sc));
            }
        }
    }
    mloc = blockReduceMax(mloc, sred);
    if (tid == 0) part[z * 4 + blockIdx.x] = mloc;
}

// ---------- attention pass 2: fused QK^T -> fq -> softmax -> uint8 grid -> PV ----------
__global__ __launch_bounds__(256, 2) void attn_fused_kernel(
    const short* __restrict__ qkvq, const short* __restrict__ vtq,
    float* __restrict__ xa,
    const float* __restrict__ part5, int np5,
    const float* __restrict__ part6, int np6,
    float* __restrict__ part) {
    __shared__ __align__(16) short Qs[64 * 64];
    __shared__ __align__(16) short UN[64 * 256];
    __shared__ __align__(16) short Vs[64 * 256];
    __shared__ float sred[4];
    const int tid = threadIdx.x, lane = tid & 63, wave = tid >> 6;
    const int z = blockIdx.z, b = z >> 4, hh = z & 15, rb = blockIdx.x;
    const float s5 = scale_v(pmax256(part5, np5, sred));
    const float s6 = scale_v(pmax256(part6, np6, sred));
    const float sc = s5 * s5 * 0.125f;
    const short* qbase = qkvq + (size_t)b * NSEQ * QKVD + hh * 64;
    const short* kbase = qbase + 1024;

    #pragma unroll
    for (int i = 0; i < 2; i++) {
        int c = tid + 256 * i;
        int r = c >> 3, sl = c & 7;
        int gr = min(rb * 64 + r, NSEQ - 1);
        GLL(qbase + (size_t)gr * QKVD + ((sl ^ (r & 7)) * 8), Qs + c * 8);
    }
    #pragma unroll
    for (int i = 0; i < 7; i++) {
        int c = tid + 256 * i;
        int n = c >> 3, sl = c & 7;
        int gn = min(n, NSEQ - 1);
        GLL(kbase + (size_t)gn * QKVD + ((sl ^ (n & 7)) * 8), UN + c * 8);
    }
    {
        const short* vsrc = vtq + (size_t)z * 64 * 256;
        #pragma unroll
        for (int i = 0; i < 8; i++) {
            int c = tid + 256 * i;
            GLL(vsrc + c * 8, Vs + c * 8);
        }
    }
    __syncthreads();

    const int lr = lane & 15, klane = lane >> 4;
    f32x4 acc[14];
    #pragma unroll
    for (int cb = 0; cb < 14; cb++) acc[cb] = (f32x4){0.f, 0.f, 0.f, 0.f};
    #pragma unroll
    for (int ks = 0; ks < 2; ks++) {
        int r = wave * 16 + lr;
        bf16x8 aq = *(const bf16x8*)&Qs[r * 64 + (((ks * 4 + klane) ^ (r & 7)) * 8)];
        #pragma unroll
        for (int cb = 0; cb < 14; cb++) {
            int n = cb * 16 + lr;
            bf16x8 bk = *(const bf16x8*)&UN[n * 64 + (((ks * 4 + klane) ^ (n & 7)) * 8)];
            acc[cb] = __builtin_amdgcn_mfma_f32_16x16x32_bf16(aq, bk, acc[cb], 0, 0, 0);
        }
    }
    __syncthreads();

    #pragma unroll
    for (int reg = 0; reg < 4; reg++) {
        int rloc = wave * 16 + klane * 4 + reg;
        float v[14], mx = -3.0e38f;
        #pragma unroll
        for (int cb = 0; cb < 14; cb++) {
            int col = cb * 16 + lr;
            float q = fqv(acc[cb][reg] * sc, s6);
            v[cb] = (col < NSEQ) ? q : -3.0e38f;
            mx = fmaxf(mx, v[cb]);
        }
        #pragma unroll
        for (int o = 8; o > 0; o >>= 1) mx = fmaxf(mx, __shfl_xor(mx, o));
        float e[14], sum = 0.f;
        #pragma unroll
        for (int cb = 0; cb < 14; cb++) {
            int col = cb * 16 + lr;
            e[cb] = (col < NSEQ) ? expf(v[cb] - mx) : 0.f;
            sum += e[cb];
        }
        #pragma unroll
        for (int o = 8; o > 0; o >>= 1) sum += __shfl_xor(sum, o);
        #pragma unroll
        for (int cb = 0; cb < 14; cb++) {
            int col = cb * 16 + lr;
            float plvl = (col < NSEQ) ? rintf(e[cb] / sum * 255.0f) : 0.f;
            UN[rloc * 256 + (((col >> 3) ^ (rloc & 7)) * 8) + (col & 7)] = bf16_of_small_int(plvl);
        }
    }
    __syncthreads();

    f32x4 acc2[4];
    #pragma unroll
    for (int j = 0; j < 4; j++) acc2[j] = (f32x4){0.f, 0.f, 0.f, 0.f};
    #pragma unroll
    for (int ks = 0; ks < 7; ks++) {
        int r = wave * 16 + lr;
        bf16x8 ap = *(const bf16x8*)&UN[r * 256 + (((ks * 4 + klane) ^ (r & 7)) * 8)];
        #pragma unroll
        for (int j = 0; j < 4; j++) {
            int d = j * 16 + lr;
            bf16x8 bv = *(const bf16x8*)&Vs[d * 256 + (((ks * 4 + klane) ^ (d & 7)) * 8)];
            acc2[j] = __builtin_amdgcn_mfma_f32_16x16x32_bf16(ap, bv, acc2[j], 0, 0, 0);
        }
    }
    const float sc2 = s5 * (1.0f / 255.0f);
    float mloc = 0.f;
    #pragma unroll
    for (int j = 0; j < 4; j++) {
        int d = j * 16 + lr;
        #pragma unroll
        for (int r = 0; r < 4; r++) {
            int grow = rb * 64 + wave * 16 + klane * 4 + r;
            if (grow < NSEQ) {
                float vv = acc2[j][r] * sc2;
                xa[((size_t)b * NSEQ + grow) * CDIM + hh * 64 + d] = vv;
                mloc = fmaxf(mloc, fabsf(vv));
            }
        }
    }
    mloc = blockReduceMax(mloc, sred);
    if (tid == 0) part[z * 4 + rb] = mloc;
}

// ---------- i8 MFMA GEMM, 4-wave 64x128 "small" (fc2, proj) ----------
template <int EPI>
__global__ __launch_bounds__(256, 4) void mfma_gemmS_kernel(
    const signed char* __restrict__ Aq, const signed char* __restrict__ Bq,
    const float* __restrict__ bias, float* __restrict__ C,
    int M, int N, int K, int NBX,
    const float* __restrict__ partA, int nA,
    const float* __restrict__ amB, float* __restrict__ partOut) {
    __shared__ __align__(16) signed char As[2][64 * 64];
    __shared__ __align__(16) signed char Bs[2][128 * 64];
    __shared__ float sred[4];
    const int tid = threadIdx.x;
    const int lane = tid & 63;
    const int wave = tid >> 6;           // 0..3
    const int wg = (blockIdx.x & 7) * ((int)gridDim.x >> 3) + ((int)blockIdx.x >> 3);
    const int n0 = (wg % NBX) * 128;
    const int m0 = (wg / NBX) * 64;
    const int wm = (wave >> 1) * 32;     // 0,32
    const int wn = (wave & 1) * 64;      // 0,64

    i32x4 acc[2][4] = {};

    const signed char* gA;
    {
        int row = tid >> 2;
        int gsl = ((tid & 3) ^ (row & 3)) * 16;
        gA = Aq + (size_t)(m0 + row) * K + gsl;
    }
    const signed char* gB[2];
    #pragma unroll
    for (int i = 0; i < 2; i++) {
        int s = tid + 256 * i;
        int row = s >> 2;
        int gsl = ((s & 3) ^ (row & 3)) * 16;
        gB[i] = Bq + (size_t)(n0 + row) * K + gsl;
    }
    const int lr = lane & 15;
    const int klane = lane >> 4;
    int offA[2], offB[4];
    #pragma unroll
    for (int i = 0; i < 2; i++) {
        int ra = wm + i * 16 + lr;
        offA[i] = ra * 64 + ((klane ^ (ra & 3)) * 16);
    }
    #pragma unroll
    for (int j = 0; j < 4; j++) {
        int rb = wn + j * 16 + lr;
        offB[j] = rb * 64 + ((klane ^ (rb & 3)) * 16);
    }

#define STAGES(buf, kk) do { \
    GLL(gA + (kk),    &As[buf][wave * 1024]); \
    GLL(gB[0] + (kk), &Bs[buf][wave * 1024]); \
    GLL(gB[1] + (kk), &Bs[buf][wave * 1024 + 4096]); \
} while (0)

#define COMPUTES(buf) do { \
    i32x4 a[2], b[4]; \
    _Pragma("unroll") \
    for (int i = 0; i < 2; i++) a[i] = *(const i32x4*)&As[buf][offA[i]]; \
    _Pragma("unroll") \
    for (int j = 0; j < 4; j++) b[j] = *(const i32x4*)&Bs[buf][offB[j]]; \
    _Pragma("unroll") \
    for (int i = 0; i < 2; i++) \
        _Pragma("unroll") \
        for (int j = 0; j < 4; j++) \
            acc[i][j] = __builtin_amdgcn_mfma_i32_16x16x64_i8(a[i], b[j], acc[i][j], 0, 0, 0); \
} while (0)

    STAGES(0, 0);
    __syncthreads();
    int k0 = 0;
    for (; k0 + 128 < K; k0 += 128) {
        STAGES(1, k0 + 64);
        COMPUTES(0);
        __syncthreads();
        STAGES(0, k0 + 128);
        COMPUTES(1);
        __syncthreads();
    }
    STAGES(1, k0 + 64);
    COMPUTES(0);
    __syncthreads();
    COMPUTES(1);
#undef STAGES
#undef COMPUTES

    const float sAB = scale_v(pmax256(partA, nA, sred)) * scale_of(amB);
    const int cr = (lane >> 4) * 4;
    const int cc = lane & 15;
    float mloc = 0.f;
    #pragma unroll
    for (int i = 0; i < 2; i++) {
        #pragma unroll
        for (int j = 0; j < 4; j++) {
            int gn = n0 + wn + j * 16 + cc;
            float bv = bias[gn];
            #pragma unroll
            for (int r = 0; r < 4; r++) {
                int gm = m0 + wm + i * 16 + cr + r;
                if (gm >= M) continue;
                float v = (float)acc[i][j][r] * sAB + bv;
                if (EPI == 1) v = gelu_f(v);
                C[(size_t)gm * N + gn] = v;
                mloc = fmaxf(mloc, fabsf(v));
            }
        }
    }
    mloc = blockReduceMax(mloc, sred);
    if (tid == 0) partOut[blockIdx.x] = mloc;
}

// ---------- i8 MFMA GEMM, 8-wave 256x128 (qkv, fc1) ----------
template <int EPI>
__global__ __launch_bounds__(512, 4) void mfma_gemm8_kernel(
    const signed char* __restrict__ Aq, const signed char* __restrict__ Bq,
    const float* __restrict__ bias, float* __restrict__ C,
    int M, int N, int K, int NBX,
    const float* __restrict__ amA, const float* __restrict__ amB,
    float* __restrict__ partOut) {
    __shared__ __align__(16) signed char As[2][256 * 64];
    __shared__ __align__(16) signed char Bs[2][128 * 64];
    __shared__ float sred[8];
    const int tid = threadIdx.x;
    const int lane = tid & 63;
    const int wave = tid >> 6;
    const int wg = (blockIdx.x & 7) * ((int)gridDim.x >> 3) + ((int)blockIdx.x >> 3);
    const int n0 = (wg % NBX) * 128;
    const int m0 = (wg / NBX) * 256;
    const int wm = (wave >> 1) * 64;
    const int wn = (wave & 1) * 64;
    const float sAB = scale_of(amA) * scale_of(amB);

    i32x4 acc[4][4] = {};

    const signed char* gA[2];
    #pragma unroll
    for (int i = 0; i < 2; i++) {
        int s = tid + 512 * i;
        int row = s >> 2;
        int gsl = ((s & 3) ^ (row & 3)) * 16;
        gA[i] = Aq + (size_t)(m0 + row) * K + gsl;
    }
    const signed char* gB;
    {
        int row = tid >> 2;
        int gsl = ((tid & 3) ^ (row & 3)) * 16;
        gB = Bq + (size_t)(n0 + row) * K + gsl;
    }
    const int lr = lane & 15;
    const int klane = lane >> 4;
    int offA[4], offB[4];
    #pragma unroll
    for (int i = 0; i < 4; i++) {
        int ra = wm + i * 16 + lr;
        int rb = wn + i * 16 + lr;
        offA[i] = ra * 64 + ((klane ^ (ra & 3)) * 16);
        offB[i] = rb * 64 + ((klane ^ (rb & 3)) * 16);
    }

#define STAGE(buf, kk) do { \
    GLL(gA[0] + (kk), &As[buf][wave * 1024]); \
    GLL(gA[1] + (kk), &As[buf][wave * 1024 + 8192]); \
    GLL(gB + (kk),    &Bs[buf][wave * 1024]); \
} while (0)

#define COMPUTE(buf) do { \
    i32x4 a[4], b[4]; \
    _Pragma("unroll") \
    for (int i = 0; i < 4; i++) { \
        a[i] = *(const i32x4*)&As[buf][offA[i]]; \
        b[i] = *(const i32x4*)&Bs[buf][offB[i]]; \
    } \
    _Pragma("unroll") \
    for (int i = 0; i < 4; i++) \
        _Pragma("unroll") \
        for (int j = 0; j < 4; j++) \
            acc[i][j] = __builtin_amdgcn_mfma_i32_16x16x64_i8(a[i], b[j], acc[i][j], 0, 0, 0); \
} while (0)

    STAGE(0, 0);
    __syncthreads();
    int k0 = 0;
    for (; k0 + 128 < K; k0 += 128) {
        STAGE(1, k0 + 64);
        COMPUTE(0);
        __syncthreads();
        STAGE(0, k0 + 128);
        COMPUTE(1);
        __syncthreads();
    }
    STAGE(1, k0 + 64);
    COMPUTE(0);
    __syncthreads();
    COMPUTE(1);
#undef STAGE
#undef COMPUTE

    const int cr = (lane >> 4) * 4;
    const int cc = lane & 15;
    float mloc = 0.f;
    #pragma unroll
    for (int i = 0; i < 4; i++) {
        #pragma unroll
        for (int j = 0; j < 4; j++) {
            int gn = n0 + wn + j * 16 + cc;
            float bv = bias[gn];
            #pragma unroll
            for (int r = 0; r < 4; r++) {
                int gm = m0 + wm + i * 16 + cr + r;
                if (gm >= M) continue;
                float v = (float)acc[i][j][r] * sAB + bv;
                if (EPI == 1) v = gelu_f(v);
                C[(size_t)gm * N + gn] = v;
                mloc = fmaxf(mloc, fabsf(v));
            }
        }
    }
    mloc = blockReduceMax8(mloc, sred);
    if (tid == 0) partOut[blockIdx.x] = mloc;
}

// ---------- launcher ----------
extern "C" void kernel_launch(void* const* d_in, const int* in_sizes, int n_in,
                              void* d_out, int out_size, void* d_ws, size_t ws_size,
                              hipStream_t stream) {
    (void)in_sizes; (void)n_in; (void)out_size; (void)ws_size;
    const float* x      = (const float*)d_in[0];
    const float* g1     = (const float*)d_in[1];
    const float* b1     = (const float*)d_in[2];
    const float* w_qkv  = (const float*)d_in[3];
    const float* b_qkv  = (const float*)d_in[4];
    const float* w_proj = (const float*)d_in[5];
    const float* b_proj = (const float*)d_in[6];
    const float* g2     = (const float*)d_in[7];
    const float* b2     = (const float*)d_in[8];
    const float* w_fc1  = (const float*)d_in[9];
    const float* b_fc1  = (const float*)d_in[10];
    const float* w_fc2  = (const float*)d_in[11];
    const float* b_fc2  = (const float*)d_in[12];
    float* out = (float*)d_out;
    float* ws  = (float*)d_ws;

    float* am       = ws;                  // 64 (slots 0..4 by reduce_am5, 10 by reduce_one)
    float* partP    = ws + 64;             // 16384 (prep)
    float* p_qkv    = partP + 16384;       // 1024 (600 used)
    float* p_s      = p_qkv + 1024;        // 2048
    float* p_xa     = p_s + 2048;          // 2048
    float* p_proj   = p_xa + 2048;         // 1024 (800 used)
    float* p_y      = p_proj + 1024;       // 2048
    float* p_ln     = p_y + 2048;          // 6400 (ROWS)
    float* p_fc1    = p_ln + 6400;         // 1024 (800)
    float* p_fc2    = p_fc1 + 1024;        // 1024 (800)
    float* p_r2     = p_fc2 + 1024;        // 2048
    signed char* wq_qkv  = (signed char*)(p_r2 + 2048);
    signed char* wq_proj = wq_qkv + (size_t)QKVD * CDIM;
    signed char* wq_fc1  = wq_proj + (size_t)CDIM * CDIM;
    signed char* wq_fc2  = wq_fc1 + (size_t)FFD * CDIM;
    signed char* xnq     = wq_fc2 + (size_t)CDIM * FFD;
    float* y             = (float*)(xnq + (size_t)MPAD * CDIM);
    short* qkvq          = (short*)(y + (size_t)ROWS * CDIM);
    float* qkvF          = (float*)(qkvq + (size_t)ROWS * QKVD);
    short* vtq           = (short*)y;
    float* h             = (float*)qkvq;
    signed char* hq      = (signed char*)(h + (size_t)ROWS * FFD);
    float* xa = out;

    // prep: partial maxima -> 1-block reduce -> quant passes (+ xnq pad-zero blocks)
    prep_a_kernel<<<NPREP, 256, 0, stream>>>(w_qkv, w_proj, w_fc1, w_fc2, x, g1, b1, partP);
    reduce_am5_kernel<<<1, 256, 0, stream>>>(partP, am);
    prep_b_kernel<<<NPREP + (MPAD - ROWS), 256, 0, stream>>>(
        w_qkv, wq_qkv, w_proj, wq_proj, w_fc1, wq_fc1, w_fc2, wq_fc2,
        x, g1, b1, xnq, am);

    // qkv (8-wave 256x128, grid 600) -> p_qkv partials
    mfma_gemm8_kernel<0><<<600, 512, 0, stream>>>(
        xnq, wq_qkv, b_qkv, qkvF, ROWS, QKVD, CDIM, QKVD / 128, am + 4, am + 0, p_qkv);
    qv_kernel<<<2048 + NBH, 256, 0, stream>>>(qkvF, qkvq, vtq, p_qkv, 600);

    // attention: amax(S) partials -> fused (inline reduces) -> p_xa partials
    attn_amax_kernel<<<dim3(4, 1, NBH), 256, 0, stream>>>(qkvq, p_qkv, 600, p_s);
    attn_fused_kernel<<<dim3(4, 1, NBH), 256, 0, stream>>>(
        qkvq, vtq, xa, p_qkv, 600, p_s, NBH * 4, p_xa);

    // proj (64x128 small-tile, grid 800, inline amA) -> p_proj
    quant_i8_kernel<<<2048, 256, 0, stream>>>(xa, xnq,
        (long long)ROWS * CDIM / 4, (long long)MPAD * CDIM / 4, p_xa, NBH * 4);
    mfma_gemmS_kernel<0><<<800, 256, 0, stream>>>(
        xnq, wq_proj, b_proj, y, ROWS, CDIM, CDIM, CDIM / 128, p_xa, NBH * 4, am + 1, p_proj);

    // residual 1: y = x + fq(y, s(p_proj)); -> p_y
    addfq_kernel<<<2048, 256, 0, stream>>>(x, nullptr, 0, y, (long long)ROWS * CDIM / 4,
                                           p_proj, 800, p_y);

    // LN2: partial amax -> reduce -> recompute-quant
    ln_kernel<0><<<ROWS, 256, 0, stream>>>(y, g2, b2, nullptr, p_y, 2048, nullptr, p_ln);
    reduce_one_kernel<<<1, 256, 0, stream>>>(p_ln, ROWS, am + 10);
    ln_kernel<1><<<ROWS, 256, 0, stream>>>(y, g2, b2, xnq, p_y, 2048, am + 10, nullptr);

    // fc1 (gelu epilogue) -> p_fc1
    mfma_gemm8_kernel<1><<<800, 512, 0, stream>>>(
        xnq, wq_fc1, b_fc1, h, ROWS, FFD, CDIM, FFD / 128, am + 10, am + 2, p_fc1);
    quant_i8_kernel<<<4096, 256, 0, stream>>>(h, hq,
        (long long)ROWS * FFD / 4, (long long)MPAD * FFD / 4, p_fc1, 800);

    // fc2 (64x128 small-tile, grid 800, inline amA) -> p_fc2
    mfma_gemmS_kernel<0><<<800, 256, 0, stream>>>(
        hq, wq_fc2, b_fc2, out, ROWS, CDIM, FFD, CDIM / 128, p_fc1, 800, am + 3, p_fc2);

    // residual 2: out = fq(y,s(p_y)) + fq(out,s(p_fc2)) -> p_r2; final fq
    addfq_kernel<<<2048, 256, 0, stream>>>(y, p_y, 2048, out, (long long)ROWS * CDIM / 4,
                                           p_fc2, 800, p_r2);
    fq_inplace_kernel<<<2048, 256, 0, stream>>>(out, (long long)ROWS * CDIM / 4, p_r2, 2048);
}

// Round 19
// 445.873 us; speedup vs baseline: 1.0099x; 1.0099x over previous
//
#include <hip/hip_runtime.h>

#define ROWS 6304      // B*N = 32*197
#define MPAD 6400      // 50 * 128
#define CDIM 1024
#define QKVD 3072
#define FFD  4096
#define NSEQ 197
#define NBH  512       // B*H
#define NPREP (3072 + ROWS)   // 9376

typedef __attribute__((ext_vector_type(8))) short bf16x8;
typedef __attribute__((ext_vector_type(4))) float f32x4;
typedef __attribute__((ext_vector_type(4))) int i32x4;

// ---------- device helpers ----------
__device__ __forceinline__ float fqv(float v, float s) {
    float q = rintf(v / s);
    q = fminf(fmaxf(q, -127.0f), 127.0f);
    return q * s;
}
__device__ __forceinline__ float gelu_f(float x) {
    const float c = 0.7978845608028654f;  // sqrt(2/pi)
    float t = tanhf(c * (x + 0.044715f * x * x * x));
    return 0.5f * x * (1.0f + t);
}
__device__ __forceinline__ short bf16_of_small_int(float q) {
    return (short)(__float_as_uint(q) >> 16);  // exact for |q| <= 255 integers
}
__device__ __forceinline__ short q_bf16(float v, float s) {
    return bf16_of_small_int(fminf(fmaxf(rintf(v / s), -127.f), 127.f));
}
// block = 256 threads (4 waves)
__device__ __forceinline__ float blockReduceSum(float v, float* sred) {
    int lane = threadIdx.x & 63, w = threadIdx.x >> 6;
    #pragma unroll
    for (int o = 32; o > 0; o >>= 1) v += __shfl_down(v, o);
    __syncthreads();
    if (lane == 0) sred[w] = v;
    __syncthreads();
    return sred[0] + sred[1] + sred[2] + sred[3];
}
__device__ __forceinline__ float blockReduceMax(float v, float* sred) {
    int lane = threadIdx.x & 63, w = threadIdx.x >> 6;
    #pragma unroll
    for (int o = 32; o > 0; o >>= 1) v = fmaxf(v, __shfl_down(v, o));
    __syncthreads();
    if (lane == 0) sred[w] = v;
    __syncthreads();
    return fmaxf(fmaxf(sred[0], sred[1]), fmaxf(sred[2], sred[3]));
}
// block = 512 threads (8 waves)
__device__ __forceinline__ float blockReduceMax8(float v, float* sred) {
    int lane = threadIdx.x & 63, w = threadIdx.x >> 6;
    #pragma unroll
    for (int o = 32; o > 0; o >>= 1) v = fmaxf(v, __shfl_down(v, o));
    __syncthreads();
    if (lane == 0) sred[w] = v;
    __syncthreads();
    float m = sred[0];
    #pragma unroll
    for (int i = 1; i < 8; i++) m = fmaxf(m, sred[i]);
    return m;
}
// inline amax over a partials array (256-thread blocks), broadcast to all threads
__device__ __forceinline__ float pmax256(const float* part, int n, float* sred) {
    float m = 0.f;
    for (int i = threadIdx.x; i < n; i += 256) m = fmaxf(m, part[i]);
    return blockReduceMax(m, sred);
}
__device__ __forceinline__ float scale_v(float amv) {
    return fmaxf(amv / 127.0f, 1e-8f);
}
__device__ __forceinline__ float scale_of(const float* am) {
    return fmaxf(am[0] / 127.0f, 1e-8f);
}

// ---------- prep_a: weight absmax (blocks 0..3071) || LN1 amax (3072..9375) ----------
__global__ __launch_bounds__(256) void prep_a_kernel(
    const float* __restrict__ w0, const float* __restrict__ w1,
    const float* __restrict__ w2, const float* __restrict__ w3,
    const float* __restrict__ x, const float* __restrict__ g1,
    const float* __restrict__ b1, float* __restrict__ part) {
    __shared__ float sred[4];
    int b = blockIdx.x, tid = threadIdx.x;
    if (b < 3072) {
        const float4* p; int base, nb;
        if (b < 768)       { p = (const float4*)w0; base = b;        nb = 768;  }
        else if (b < 1024) { p = (const float4*)w1; base = b - 768;  nb = 256;  }
        else if (b < 2048) { p = (const float4*)w2; base = b - 1024; nb = 1024; }
        else               { p = (const float4*)w3; base = b - 2048; nb = 1024; }
        float m = 0.f;
        #pragma unroll
        for (int it = 0; it < 4; it++) {
            float4 v = p[(long long)it * nb * 256 + (long long)base * 256 + tid];
            m = fmaxf(m, fmaxf(fmaxf(fabsf(v.x), fabsf(v.y)), fmaxf(fabsf(v.z), fabsf(v.w))));
        }
        m = blockReduceMax(m, sred);
        if (tid == 0) part[b] = m;
    } else {
        int row = b - 3072;
        float4 v = ((const float4*)(x + (size_t)row * CDIM))[tid];
        float sum = blockReduceSum(v.x + v.y + v.z + v.w, sred);
        float mu = sum * (1.0f / CDIM);
        float dx = v.x - mu, dy = v.y - mu, dz = v.z - mu, dw = v.w - mu;
        float var = blockReduceSum(dx * dx + dy * dy + dz * dz + dw * dw, sred) * (1.0f / CDIM);
        float rstd = rsqrtf(var + 1e-6f);
        float4 gv = ((const float4*)g1)[tid], bv = ((const float4*)b1)[tid];
        float ox = dx * rstd * gv.x + bv.x;
        float oy = dy * rstd * gv.y + bv.y;
        float oz = dz * rstd * gv.z + bv.z;
        float ow = dw * rstd * gv.w + bv.w;
        float m = fmaxf(fmaxf(fabsf(ox), fabsf(oy)), fmaxf(fabsf(oz), fabsf(ow)));
        m = blockReduceMax(m, sred);
        if (tid == 0) part[b] = m;
    }
}

// one block: collapse prep_a partials into am[0..4] (sole writer, plain stores)
__global__ __launch_bounds__(256) void reduce_am5_kernel(const float* __restrict__ part,
                                                         float* __restrict__ am) {
    __shared__ float sred[4];
    float m0 = 0.f, m1 = 0.f, m2 = 0.f, m3 = 0.f, m4 = 0.f;
    for (int i = threadIdx.x; i < NPREP; i += 256) {
        float v = part[i];
        if (i < 768) m0 = fmaxf(m0, v);
        else if (i < 1024) m1 = fmaxf(m1, v);
        else if (i < 2048) m2 = fmaxf(m2, v);
        else if (i < 3072) m3 = fmaxf(m3, v);
        else m4 = fmaxf(m4, v);
    }
    m0 = blockReduceMax(m0, sred);
    m1 = blockReduceMax(m1, sred);
    m2 = blockReduceMax(m2, sred);
    m3 = blockReduceMax(m3, sred);
    m4 = blockReduceMax(m4, sred);
    if (threadIdx.x == 0) { am[0] = m0; am[1] = m1; am[2] = m2; am[3] = m3; am[4] = m4; }
}

// one block: amDst[0] = max(part[0..n))
__global__ __launch_bounds__(256) void reduce_one_kernel(const float* __restrict__ part,
                                                         int n, float* __restrict__ amDst) {
    __shared__ float sred[4];
    float m = 0.f;
    for (int i = threadIdx.x; i < n; i += 256) m = fmaxf(m, part[i]);
    m = blockReduceMax(m, sred);
    if (threadIdx.x == 0) amDst[0] = m;
}

// ---------- prep_b: weight quant || LN1 recompute-quant || xnq pad-zero ----------
__global__ __launch_bounds__(256) void prep_b_kernel(
    const float* __restrict__ w0, signed char* __restrict__ d0,
    const float* __restrict__ w1, signed char* __restrict__ d1,
    const float* __restrict__ w2, signed char* __restrict__ d2,
    const float* __restrict__ w3, signed char* __restrict__ d3,
    const float* __restrict__ x, const float* __restrict__ g1,
    const float* __restrict__ b1, signed char* __restrict__ xnq,
    const float* __restrict__ am) {
    __shared__ float sred[4];
    int b = blockIdx.x, tid = threadIdx.x;
    if (b >= NPREP) {
        int row = ROWS + (b - NPREP);
        ((int*)xnq)[(size_t)row * (CDIM / 4) + tid] = 0;
        return;
    }
    if (b < 3072) {
        const float4* p; int* d; int base, nb; float s;
        if (b < 768)       { p = (const float4*)w0; d = (int*)d0; base = b;        nb = 768;  s = scale_of(am + 0); }
        else if (b < 1024) { p = (const float4*)w1; d = (int*)d1; base = b - 768;  nb = 256;  s = scale_of(am + 1); }
        else if (b < 2048) { p = (const float4*)w2; d = (int*)d2; base = b - 1024; nb = 1024; s = scale_of(am + 2); }
        else               { p = (const float4*)w3; d = (int*)d3; base = b - 2048; nb = 1024; s = scale_of(am + 3); }
        #pragma unroll
        for (int it = 0; it < 4; it++) {
            long long i = (long long)it * nb * 256 + (long long)base * 256 + tid;
            float4 v = p[i];
            int q0 = (int)fminf(fmaxf(rintf(v.x / s), -127.f), 127.f);
            int q1 = (int)fminf(fmaxf(rintf(v.y / s), -127.f), 127.f);
            int q2 = (int)fminf(fmaxf(rintf(v.z / s), -127.f), 127.f);
            int q3 = (int)fminf(fmaxf(rintf(v.w / s), -127.f), 127.f);
            d[i] = (q0 & 255) | ((q1 & 255) << 8) | ((q2 & 255) << 16) | (q3 << 24);
        }
    } else {
        int row = b - 3072;
        float4 v = ((const float4*)(x + (size_t)row * CDIM))[tid];
        float sum = blockReduceSum(v.x + v.y + v.z + v.w, sred);
        float mu = sum * (1.0f / CDIM);
        float dx = v.x - mu, dy = v.y - mu, dz = v.z - mu, dw = v.w - mu;
        float var = blockReduceSum(dx * dx + dy * dy + dz * dz + dw * dw, sred) * (1.0f / CDIM);
        float rstd = rsqrtf(var + 1e-6f);
        float4 gv = ((const float4*)g1)[tid], bv = ((const float4*)b1)[tid];
        float ox = dx * rstd * gv.x + bv.x;
        float oy = dy * rstd * gv.y + bv.y;
        float oz = dz * rstd * gv.z + bv.z;
        float ow = dw * rstd * gv.w + bv.w;
        float s = scale_of(am + 4);
        int q0 = (int)fminf(fmaxf(rintf(ox / s), -127.f), 127.f);
        int q1 = (int)fminf(fmaxf(rintf(oy / s), -127.f), 127.f);
        int q2 = (int)fminf(fmaxf(rintf(oz / s), -127.f), 127.f);
        int q3 = (int)fminf(fmaxf(rintf(ow / s), -127.f), 127.f);
        ((int*)xnq)[(size_t)row * (CDIM / 4) + tid] =
            (q0 & 255) | ((q1 & 255) << 8) | ((q2 & 255) << 16) | (q3 << 24);
    }
}

// ---------- LayerNorm (LN2): MODE 0 partial amax; MODE 1 recompute-quant ----------
template <int MODE>
__global__ __launch_bounds__(256) void ln_kernel(
    const float* __restrict__ x, const float* __restrict__ g,
    const float* __restrict__ bb, signed char* __restrict__ dst,
    const float* __restrict__ partIn, int nIn,
    const float* __restrict__ amQ, float* __restrict__ part) {
    __shared__ float sred[4];
    int row = blockIdx.x;
    int t = threadIdx.x;
    float sIn = scale_v(pmax256(partIn, nIn, sred));
    float4 v = ((const float4*)(x + (size_t)row * CDIM))[t];
    v.x = fqv(v.x, sIn); v.y = fqv(v.y, sIn); v.z = fqv(v.z, sIn); v.w = fqv(v.w, sIn);
    float sum = blockReduceSum(v.x + v.y + v.z + v.w, sred);
    float mu = sum * (1.0f / CDIM);
    float dx = v.x - mu, dy = v.y - mu, dz = v.z - mu, dw = v.w - mu;
    float var = blockReduceSum(dx * dx + dy * dy + dz * dz + dw * dw, sred) * (1.0f / CDIM);
    float rstd = rsqrtf(var + 1e-6f);
    float4 gv = ((const float4*)g)[t], bv = ((const float4*)bb)[t];
    float ox = dx * rstd * gv.x + bv.x;
    float oy = dy * rstd * gv.y + bv.y;
    float oz = dz * rstd * gv.z + bv.z;
    float ow = dw * rstd * gv.w + bv.w;
    if (MODE == 0) {
        float m = fmaxf(fmaxf(fabsf(ox), fabsf(oy)), fmaxf(fabsf(oz), fabsf(ow)));
        m = blockReduceMax(m, sred);
        if (t == 0) part[row] = m;
    } else {
        float s = scale_of(amQ);
        int q0 = (int)fminf(fmaxf(rintf(ox / s), -127.f), 127.f);
        int q1 = (int)fminf(fmaxf(rintf(oy / s), -127.f), 127.f);
        int q2 = (int)fminf(fmaxf(rintf(oz / s), -127.f), 127.f);
        int q3 = (int)fminf(fmaxf(rintf(ow / s), -127.f), 127.f);
        ((int*)dst)[(size_t)row * (CDIM / 4) + t] =
            (q0 & 255) | ((q1 & 255) << 8) | ((q2 & 255) << 16) | (q3 << 24);
    }
}

// final fq: s from partials
__global__ __launch_bounds__(256) void fq_inplace_kernel(float* __restrict__ buf, long long n4,
                                                         const float* __restrict__ part, int np) {
    __shared__ float sred[4];
    float s = scale_v(pmax256(part, np, sred));
    float4* b4 = (float4*)buf;
    long long stride = (long long)gridDim.x * blockDim.x;
    for (long long i = (long long)blockIdx.x * blockDim.x + threadIdx.x; i < n4; i += stride) {
        float4 v = b4[i];
        v.x = fqv(v.x, s); v.y = fqv(v.y, s); v.z = fqv(v.z, s); v.w = fqv(v.w, s);
        b4[i] = v;
    }
}

// buf[i] = FQ?(xin[i], sX) + fq(buf[i], s); scales from partials; partOut[bid] = block max
__global__ __launch_bounds__(256) void addfq_kernel(const float* __restrict__ xin,
                                                    const float* __restrict__ partX, int nX,
                                                    float* __restrict__ buf, long long n4,
                                                    const float* __restrict__ partAm, int nAm,
                                                    float* __restrict__ partOut) {
    __shared__ float sred[4];
    float s = scale_v(pmax256(partAm, nAm, sred));
    float sx = partX ? scale_v(pmax256(partX, nX, sred)) : 0.f;
    const float4* x4 = (const float4*)xin;
    float4* b4 = (float4*)buf;
    float m = 0.f;
    long long stride = (long long)gridDim.x * blockDim.x;
    for (long long i = (long long)blockIdx.x * blockDim.x + threadIdx.x; i < n4; i += stride) {
        float4 v = x4[i];
        if (partX) { v.x = fqv(v.x, sx); v.y = fqv(v.y, sx); v.z = fqv(v.z, sx); v.w = fqv(v.w, sx); }
        float4 u = b4[i];
        u.x = v.x + fqv(u.x, s);
        u.y = v.y + fqv(u.y, s);
        u.z = v.z + fqv(u.z, s);
        u.w = v.w + fqv(u.w, s);
        b4[i] = u;
        m = fmaxf(m, fmaxf(fmaxf(fabsf(u.x), fabsf(u.y)), fmaxf(fabsf(u.z), fabsf(u.w))));
    }
    m = blockReduceMax(m, sred);
    if (threadIdx.x == 0) partOut[blockIdx.x] = m;
}

// quantize to i8 levels, scale from partials, zeros for i>=n
__global__ __launch_bounds__(256) void quant_i8_kernel(const float* __restrict__ src,
                                                       signed char* __restrict__ dst,
                                                       long long n4, long long npad4,
                                                       const float* __restrict__ part, int np) {
    __shared__ float sred[4];
    float s = scale_v(pmax256(part, np, sred));
    long long stride = (long long)gridDim.x * blockDim.x;
    for (long long i = (long long)blockIdx.x * blockDim.x + threadIdx.x; i < npad4; i += stride) {
        float4 v = make_float4(0.f, 0.f, 0.f, 0.f);
        if (i < n4) v = ((const float4*)src)[i];
        int q0 = (int)fminf(fmaxf(rintf(v.x / s), -127.f), 127.f);
        int q1 = (int)fminf(fmaxf(rintf(v.y / s), -127.f), 127.f);
        int q2 = (int)fminf(fmaxf(rintf(v.z / s), -127.f), 127.f);
        int q3 = (int)fminf(fmaxf(rintf(v.w / s), -127.f), 127.f);
        ((int*)dst)[i] = (q0 & 255) | ((q1 & 255) << 8) | ((q2 & 255) << 16) | (q3 << 24);
    }
}

// ---------- qv: blocks [0,2048) quantize Q,K cols -> bf16 levels; [2048,2560) V-transpose ----------
__global__ __launch_bounds__(256) void qv_kernel(const float* __restrict__ qkvF,
                                                 short* __restrict__ qkvq,
                                                 short* __restrict__ vtq,
                                                 const float* __restrict__ part5, int np5) {
    __shared__ short T[NSEQ * 65];
    __shared__ float sred[4];
    float s = scale_v(pmax256(part5, np5, sred));
    int b = blockIdx.x, tid = threadIdx.x;
    if (b < 2048) {
        const long long n4 = (long long)ROWS * 512;
        for (long long i = (long long)b * 256 + tid; i < n4; i += (long long)2048 * 256) {
            long long row = i >> 9;
            int c4 = (int)(i & 511);
            float4 v = ((const float4*)(qkvF + row * QKVD))[c4];
            short4 o;
            o.x = q_bf16(v.x, s); o.y = q_bf16(v.y, s);
            o.z = q_bf16(v.z, s); o.w = q_bf16(v.w, s);
            ((short4*)(qkvq + row * QKVD))[c4] = o;
        }
    } else {
        int z = b - 2048, bb = z >> 4, hh = z & 15;
        const float* vb = qkvF + (size_t)bb * NSEQ * QKVD + 2048 + hh * 64;
        for (int c = tid; c < NSEQ * 16; c += 256) {
            int m = c >> 4, p = c & 15;
            float4 v = ((const float4*)(vb + (size_t)m * QKVD))[p];
            T[m * 65 + p * 4 + 0] = q_bf16(v.x, s);
            T[m * 65 + p * 4 + 1] = q_bf16(v.y, s);
            T[m * 65 + p * 4 + 2] = q_bf16(v.z, s);
            T[m * 65 + p * 4 + 3] = q_bf16(v.w, s);
        }
        __syncthreads();
        short* obase = vtq + (size_t)z * 64 * 256;
        for (int c = tid; c < 64 * 32; c += 256) {
            int d = c >> 5, sl = c & 31;
            int sp = sl ^ (d & 7);
            bf16x8 o;
            #pragma unroll
            for (int jj = 0; jj < 8; jj++) {
                int m = sl * 8 + jj;
                o[jj] = (m < NSEQ) ? T[m * 65 + d] : (short)0;
            }
            *(bf16x8*)&obase[d * 256 + sp * 8] = o;
        }
    }
}

#define GLL(gp, lp) __builtin_amdgcn_global_load_lds( \
    (const __attribute__((address_space(1))) void*)(gp), \
    (__attribute__((address_space(3))) void*)(lp), 16, 0, 0)

// ---------- attention pass 1: amax(S) only, s5 from partials ----------
__global__ __launch_bounds__(256, 2) void attn_amax_kernel(
    const short* __restrict__ qkvq,
    const float* __restrict__ part5, int np5, float* __restrict__ part) {
    __shared__ __align__(16) short Qs[256 * 32];
    __shared__ __align__(16) short Ks[64 * 32];
    __shared__ float sred[4];
    const int tid = threadIdx.x, lane = tid & 63, wave = tid >> 6;
    const int z = blockIdx.z, b = z >> 4, hh = z & 15;
    const int n0 = blockIdx.x * 64;
    const float s5 = scale_v(pmax256(part5, np5, sred));
    const float sc = s5 * s5 * 0.125f;
    const short* qbase = qkvq + (size_t)b * NSEQ * QKVD + hh * 64;
    const short* kbase = qbase + 1024;

    f32x4 acc[4][4] = {};
    const int piece = (tid & 3) * 8;
    const short* srcA[4];
    #pragma unroll
    for (int i = 0; i < 4; i++) {
        int row = i * 64 + (tid >> 2);
        srcA[i] = qbase + (size_t)min(row, NSEQ - 1) * QKVD + piece;
    }
    const short* srcB = kbase + (size_t)min(n0 + (tid >> 2), NSEQ - 1) * QKVD + piece;
    const int lr = lane & 15;
    const int koff = (lane >> 4) * 8;

    for (int k0 = 0; k0 < 64; k0 += 32) {
        __syncthreads();
        #pragma unroll
        for (int i = 0; i < 4; i++) GLL(srcA[i] + k0, Qs + i * 2048 + wave * 512);
        GLL(srcB + k0, Ks + wave * 512);
        __syncthreads();

        bf16x8 a[4], bfr[4];
        #pragma unroll
        for (int i = 0; i < 4; i++)
            a[i] = *(const bf16x8*)&Qs[(wave * 64 + i * 16 + lr) * 32 + koff];
        #pragma unroll
        for (int j = 0; j < 4; j++)
            bfr[j] = *(const bf16x8*)&Ks[(j * 16 + lr) * 32 + koff];
        #pragma unroll
        for (int i = 0; i < 4; i++)
            #pragma unroll
            for (int j = 0; j < 4; j++)
                acc[i][j] = __builtin_amdgcn_mfma_f32_16x16x32_bf16(a[i], bfr[j], acc[i][j], 0, 0, 0);
    }

    const int cr = (lane >> 4) * 4;
    const int cc = lane & 15;
    float mloc = 0.f;
    #pragma unroll
    for (int i = 0; i < 4; i++) {
        #pragma unroll
        for (int j = 0; j < 4; j++) {
            int gn = n0 + j * 16 + cc;
            #pragma unroll
            for (int r = 0; r < 4; r++) {
                int gm = wave * 64 + i * 16 + cr + r;
                if (gm < NSEQ && gn < NSEQ)
                    mloc = fmaxf(mloc, fabsf(acc[i][j][r] * sc));
            }
        }
    }
    mloc = blockReduceMax(mloc, sred);
    if (tid == 0) part[z * 4 + blockIdx.x] = mloc;
}

// ---------- attention pass 2: fused QK^T -> fq -> softmax -> uint8 grid -> PV ----------
__global__ __launch_bounds__(256, 2) void attn_fused_kernel(
    const short* __restrict__ qkvq, const short* __restrict__ vtq,
    float* __restrict__ xa,
    const float* __restrict__ part5, int np5,
    const float* __restrict__ part6, int np6,
    float* __restrict__ part) {
    __shared__ __align__(16) short Qs[64 * 64];
    __shared__ __align__(16) short UN[64 * 256];
    __shared__ __align__(16) short Vs[64 * 256];
    __shared__ float sred[4];
    const int tid = threadIdx.x, lane = tid & 63, wave = tid >> 6;
    const int z = blockIdx.z, b = z >> 4, hh = z & 15, rb = blockIdx.x;
    const float s5 = scale_v(pmax256(part5, np5, sred));
    const float s6 = scale_v(pmax256(part6, np6, sred));
    const float sc = s5 * s5 * 0.125f;
    const short* qbase = qkvq + (size_t)b * NSEQ * QKVD + hh * 64;
    const short* kbase = qbase + 1024;

    #pragma unroll
    for (int i = 0; i < 2; i++) {
        int c = tid + 256 * i;
        int r = c >> 3, sl = c & 7;
        int gr = min(rb * 64 + r, NSEQ - 1);
        GLL(qbase + (size_t)gr * QKVD + ((sl ^ (r & 7)) * 8), Qs + c * 8);
    }
    #pragma unroll
    for (int i = 0; i < 7; i++) {
        int c = tid + 256 * i;
        int n = c >> 3, sl = c & 7;
        int gn = min(n, NSEQ - 1);
        GLL(kbase + (size_t)gn * QKVD + ((sl ^ (n & 7)) * 8), UN + c * 8);
    }
    {
        const short* vsrc = vtq + (size_t)z * 64 * 256;
        #pragma unroll
        for (int i = 0; i < 8; i++) {
            int c = tid + 256 * i;
            GLL(vsrc + c * 8, Vs + c * 8);
        }
    }
    __syncthreads();

    const int lr = lane & 15, klane = lane >> 4;
    f32x4 acc[14];
    #pragma unroll
    for (int cb = 0; cb < 14; cb++) acc[cb] = (f32x4){0.f, 0.f, 0.f, 0.f};
    #pragma unroll
    for (int ks = 0; ks < 2; ks++) {
        int r = wave * 16 + lr;
        bf16x8 aq = *(const bf16x8*)&Qs[r * 64 + (((ks * 4 + klane) ^ (r & 7)) * 8)];
        #pragma unroll
        for (int cb = 0; cb < 14; cb++) {
            int n = cb * 16 + lr;
            bf16x8 bk = *(const bf16x8*)&UN[n * 64 + (((ks * 4 + klane) ^ (n & 7)) * 8)];
            acc[cb] = __builtin_amdgcn_mfma_f32_16x16x32_bf16(aq, bk, acc[cb], 0, 0, 0);
        }
    }
    __syncthreads();

    #pragma unroll
    for (int reg = 0; reg < 4; reg++) {
        int rloc = wave * 16 + klane * 4 + reg;
        float v[14], mx = -3.0e38f;
        #pragma unroll
        for (int cb = 0; cb < 14; cb++) {
            int col = cb * 16 + lr;
            float q = fqv(acc[cb][reg] * sc, s6);
            v[cb] = (col < NSEQ) ? q : -3.0e38f;
            mx = fmaxf(mx, v[cb]);
        }
        #pragma unroll
        for (int o = 8; o > 0; o >>= 1) mx = fmaxf(mx, __shfl_xor(mx, o));
        float e[14], sum = 0.f;
        #pragma unroll
        for (int cb = 0; cb < 14; cb++) {
            int col = cb * 16 + lr;
            e[cb] = (col < NSEQ) ? expf(v[cb] - mx) : 0.f;
            sum += e[cb];
        }
        #pragma unroll
        for (int o = 8; o > 0; o >>= 1) sum += __shfl_xor(sum, o);
        #pragma unroll
        for (int cb = 0; cb < 14; cb++) {
            int col = cb * 16 + lr;
            float plvl = (col < NSEQ) ? rintf(e[cb] / sum * 255.0f) : 0.f;
            UN[rloc * 256 + (((col >> 3) ^ (rloc & 7)) * 8) + (col & 7)] = bf16_of_small_int(plvl);
        }
    }
    __syncthreads();

    f32x4 acc2[4];
    #pragma unroll
    for (int j = 0; j < 4; j++) acc2[j] = (f32x4){0.f, 0.f, 0.f, 0.f};
    #pragma unroll
    for (int ks = 0; ks < 7; ks++) {
        int r = wave * 16 + lr;
        bf16x8 ap = *(const bf16x8*)&UN[r * 256 + (((ks * 4 + klane) ^ (r & 7)) * 8)];
        #pragma unroll
        for (int j = 0; j < 4; j++) {
            int d = j * 16 + lr;
            bf16x8 bv = *(const bf16x8*)&Vs[d * 256 + (((ks * 4 + klane) ^ (d & 7)) * 8)];
            acc2[j] = __builtin_amdgcn_mfma_f32_16x16x32_bf16(ap, bv, acc2[j], 0, 0, 0);
        }
    }
    const float sc2 = s5 * (1.0f / 255.0f);
    float mloc = 0.f;
    #pragma unroll
    for (int j = 0; j < 4; j++) {
        int d = j * 16 + lr;
        #pragma unroll
        for (int r = 0; r < 4; r++) {
            int grow = rb * 64 + wave * 16 + klane * 4 + r;
            if (grow < NSEQ) {
                float vv = acc2[j][r] * sc2;
                xa[((size_t)b * NSEQ + grow) * CDIM + hh * 64 + d] = vv;
                mloc = fmaxf(mloc, fabsf(vv));
            }
        }
    }
    mloc = blockReduceMax(mloc, sred);
    if (tid == 0) part[z * 4 + rb] = mloc;
}

// ---------- i8 MFMA GEMM, 4-wave 64x128 "small" (fc2, proj) ----------
// Counted-vmcnt depth-2 K-loop: raw s_barrier, vmcnt(3) per iter (3 loads/STAGE),
// loads issued at end of iter t for iter t+2; LDS/occupancy unchanged.
template <int EPI>
__global__ __launch_bounds__(256, 4) void mfma_gemmS_kernel(
    const signed char* __restrict__ Aq, const signed char* __restrict__ Bq,
    const float* __restrict__ bias, float* __restrict__ C,
    int M, int N, int K, int NBX,
    const float* __restrict__ partA, int nA,
    const float* __restrict__ amB, float* __restrict__ partOut) {
    __shared__ __align__(16) signed char As[2][64 * 64];
    __shared__ __align__(16) signed char Bs[2][128 * 64];
    __shared__ float sred[4];
    const int tid = threadIdx.x;
    const int lane = tid & 63;
    const int wave = tid >> 6;
    const int wg = (blockIdx.x & 7) * ((int)gridDim.x >> 3) + ((int)blockIdx.x >> 3);
    const int n0 = (wg % NBX) * 128;
    const int m0 = (wg / NBX) * 64;
    const int wm = (wave >> 1) * 32;
    const int wn = (wave & 1) * 64;

    i32x4 acc[2][4] = {};

    const signed char* gA;
    {
        int row = tid >> 2;
        int gsl = ((tid & 3) ^ (row & 3)) * 16;
        gA = Aq + (size_t)(m0 + row) * K + gsl;
    }
    const signed char* gB[2];
    #pragma unroll
    for (int i = 0; i < 2; i++) {
        int s = tid + 256 * i;
        int row = s >> 2;
        int gsl = ((s & 3) ^ (row & 3)) * 16;
        gB[i] = Bq + (size_t)(n0 + row) * K + gsl;
    }
    const int lr = lane & 15;
    const int klane = lane >> 4;
    int offA[2], offB[4];
    #pragma unroll
    for (int i = 0; i < 2; i++) {
        int ra = wm + i * 16 + lr;
        offA[i] = ra * 64 + ((klane ^ (ra & 3)) * 16);
    }
    #pragma unroll
    for (int j = 0; j < 4; j++) {
        int rb = wn + j * 16 + lr;
        offB[j] = rb * 64 + ((klane ^ (rb & 3)) * 16);
    }

#define STAGES(buf, kk) do { \
    GLL(gA + (kk),    &As[buf][wave * 1024]); \
    GLL(gB[0] + (kk), &Bs[buf][wave * 1024]); \
    GLL(gB[1] + (kk), &Bs[buf][wave * 1024 + 4096]); \
} while (0)

#define COMPUTES(buf) do { \
    i32x4 a[2], b[4]; \
    _Pragma("unroll") \
    for (int i = 0; i < 2; i++) a[i] = *(const i32x4*)&As[buf][offA[i]]; \
    _Pragma("unroll") \
    for (int j = 0; j < 4; j++) b[j] = *(const i32x4*)&Bs[buf][offB[j]]; \
    _Pragma("unroll") \
    for (int i = 0; i < 2; i++) \
        _Pragma("unroll") \
        for (int j = 0; j < 4; j++) \
            acc[i][j] = __builtin_amdgcn_mfma_i32_16x16x64_i8(a[i], b[j], acc[i][j], 0, 0, 0); \
} while (0)

    // pre-loop drain so in-loop vmcnt counts only staging loads
    asm volatile("s_waitcnt vmcnt(0)" ::: "memory");
    STAGES(0, 0);
    STAGES(1, 64);
    const int NK = K >> 6;
    for (int t = 0; t < NK; ++t) {
        if (t + 1 < NK) { asm volatile("s_waitcnt vmcnt(3)" ::: "memory"); }
        else            { asm volatile("s_waitcnt vmcnt(0)" ::: "memory"); }
        __builtin_amdgcn_sched_barrier(0);
        __builtin_amdgcn_s_barrier();     // all waves' buf-t loads landed
        COMPUTES(t & 1);
        __builtin_amdgcn_s_barrier();     // all waves done reading buf t
        if (t + 2 < NK) STAGES(t & 1, (t + 2) << 6);
    }
    __builtin_amdgcn_sched_barrier(0);
#undef STAGES
#undef COMPUTES

    const float sAB = scale_v(pmax256(partA, nA, sred)) * scale_of(amB);
    const int cr = (lane >> 4) * 4;
    const int cc = lane & 15;
    float mloc = 0.f;
    #pragma unroll
    for (int i = 0; i < 2; i++) {
        #pragma unroll
        for (int j = 0; j < 4; j++) {
            int gn = n0 + wn + j * 16 + cc;
            float bv = bias[gn];
            #pragma unroll
            for (int r = 0; r < 4; r++) {
                int gm = m0 + wm + i * 16 + cr + r;
                if (gm >= M) continue;
                float v = (float)acc[i][j][r] * sAB + bv;
                if (EPI == 1) v = gelu_f(v);
                C[(size_t)gm * N + gn] = v;
                mloc = fmaxf(mloc, fabsf(v));
            }
        }
    }
    mloc = blockReduceMax(mloc, sred);
    if (tid == 0) partOut[blockIdx.x] = mloc;
}

// ---------- i8 MFMA GEMM, 8-wave 256x128 (qkv, fc1): counted-vmcnt depth-2 ----------
template <int EPI>
__global__ __launch_bounds__(512, 4) void mfma_gemm8_kernel(
    const signed char* __restrict__ Aq, const signed char* __restrict__ Bq,
    const float* __restrict__ bias, float* __restrict__ C,
    int M, int N, int K, int NBX,
    const float* __restrict__ amA, const float* __restrict__ amB,
    float* __restrict__ partOut) {
    __shared__ __align__(16) signed char As[2][256 * 64];
    __shared__ __align__(16) signed char Bs[2][128 * 64];
    __shared__ float sred[8];
    const int tid = threadIdx.x;
    const int lane = tid & 63;
    const int wave = tid >> 6;
    const int wg = (blockIdx.x & 7) * ((int)gridDim.x >> 3) + ((int)blockIdx.x >> 3);
    const int n0 = (wg % NBX) * 128;
    const int m0 = (wg / NBX) * 256;
    const int wm = (wave >> 1) * 64;
    const int wn = (wave & 1) * 64;
    const float sAB = scale_of(amA) * scale_of(amB);

    i32x4 acc[4][4] = {};

    const signed char* gA[2];
    #pragma unroll
    for (int i = 0; i < 2; i++) {
        int s = tid + 512 * i;
        int row = s >> 2;
        int gsl = ((s & 3) ^ (row & 3)) * 16;
        gA[i] = Aq + (size_t)(m0 + row) * K + gsl;
    }
    const signed char* gB;
    {
        int row = tid >> 2;
        int gsl = ((tid & 3) ^ (row & 3)) * 16;
        gB = Bq + (size_t)(n0 + row) * K + gsl;
    }
    const int lr = lane & 15;
    const int klane = lane >> 4;
    int offA[4], offB[4];
    #pragma unroll
    for (int i = 0; i < 4; i++) {
        int ra = wm + i * 16 + lr;
        int rb = wn + i * 16 + lr;
        offA[i] = ra * 64 + ((klane ^ (ra & 3)) * 16);
        offB[i] = rb * 64 + ((klane ^ (rb & 3)) * 16);
    }

#define STAGE(buf, kk) do { \
    GLL(gA[0] + (kk), &As[buf][wave * 1024]); \
    GLL(gA[1] + (kk), &As[buf][wave * 1024 + 8192]); \
    GLL(gB + (kk),    &Bs[buf][wave * 1024]); \
} while (0)

#define COMPUTE(buf) do { \
    i32x4 a[4], b[4]; \
    _Pragma("unroll") \
    for (int i = 0; i < 4; i++) { \
        a[i] = *(const i32x4*)&As[buf][offA[i]]; \
        b[i] = *(const i32x4*)&Bs[buf][offB[i]]; \
    } \
    _Pragma("unroll") \
    for (int i = 0; i < 4; i++) \
        _Pragma("unroll") \
        for (int j = 0; j < 4; j++) \
            acc[i][j] = __builtin_amdgcn_mfma_i32_16x16x64_i8(a[i], b[j], acc[i][j], 0, 0, 0); \
} while (0)

    // pre-loop drain so in-loop vmcnt counts only staging loads
    asm volatile("s_waitcnt vmcnt(0)" ::: "memory");
    STAGE(0, 0);
    STAGE(1, 64);
    const int NK = K >> 6;
    for (int t = 0; t < NK; ++t) {
        if (t + 1 < NK) { asm volatile("s_waitcnt vmcnt(3)" ::: "memory"); }
        else            { asm volatile("s_waitcnt vmcnt(0)" ::: "memory"); }
        __builtin_amdgcn_sched_barrier(0);
        __builtin_amdgcn_s_barrier();     // all waves' buf-t loads landed
        COMPUTE(t & 1);
        __builtin_amdgcn_s_barrier();     // all waves done reading buf t
        if (t + 2 < NK) STAGE(t & 1, (t + 2) << 6);
    }
    __builtin_amdgcn_sched_barrier(0);
#undef STAGE
#undef COMPUTE

    const int cr = (lane >> 4) * 4;
    const int cc = lane & 15;
    float mloc = 0.f;
    #pragma unroll
    for (int i = 0; i < 4; i++) {
        #pragma unroll
        for (int j = 0; j < 4; j++) {
            int gn = n0 + wn + j * 16 + cc;
            float bv = bias[gn];
            #pragma unroll
            for (int r = 0; r < 4; r++) {
                int gm = m0 + wm + i * 16 + cr + r;
                if (gm >= M) continue;
                float v = (float)acc[i][j][r] * sAB + bv;
                if (EPI == 1) v = gelu_f(v);
                C[(size_t)gm * N + gn] = v;
                mloc = fmaxf(mloc, fabsf(v));
            }
        }
    }
    mloc = blockReduceMax8(mloc, sred);
    if (tid == 0) partOut[blockIdx.x] = mloc;
}

// ---------- launcher ----------
extern "C" void kernel_launch(void* const* d_in, const int* in_sizes, int n_in,
                              void* d_out, int out_size, void* d_ws, size_t ws_size,
                              hipStream_t stream) {
    (void)in_sizes; (void)n_in; (void)out_size; (void)ws_size;
    const float* x      = (const float*)d_in[0];
    const float* g1     = (const float*)d_in[1];
    const float* b1     = (const float*)d_in[2];
    const float* w_qkv  = (const float*)d_in[3];
    const float* b_qkv  = (const float*)d_in[4];
    const float* w_proj = (const float*)d_in[5];
    const float* b_proj = (const float*)d_in[6];
    const float* g2     = (const float*)d_in[7];
    const float* b2     = (const float*)d_in[8];
    const float* w_fc1  = (const float*)d_in[9];
    const float* b_fc1  = (const float*)d_in[10];
    const float* w_fc2  = (const float*)d_in[11];
    const float* b_fc2  = (const float*)d_in[12];
    float* out = (float*)d_out;
    float* ws  = (float*)d_ws;

    float* am       = ws;                  // 64 (slots 0..4 by reduce_am5, 10 by reduce_one)
    float* partP    = ws + 64;             // 16384 (prep)
    float* p_qkv    = partP + 16384;       // 1024 (600 used)
    float* p_s      = p_qkv + 1024;        // 2048
    float* p_xa     = p_s + 2048;          // 2048
    float* p_proj   = p_xa + 2048;         // 1024 (800 used)
    float* p_y      = p_proj + 1024;       // 2048
    float* p_ln     = p_y + 2048;          // 6400 (ROWS)
    float* p_fc1    = p_ln + 6400;         // 1024 (800)
    float* p_fc2    = p_fc1 + 1024;        // 1024 (800)
    float* p_r2     = p_fc2 + 1024;        // 2048
    signed char* wq_qkv  = (signed char*)(p_r2 + 2048);
    signed char* wq_proj = wq_qkv + (size_t)QKVD * CDIM;
    signed char* wq_fc1  = wq_proj + (size_t)CDIM * CDIM;
    signed char* wq_fc2  = wq_fc1 + (size_t)FFD * CDIM;
    signed char* xnq     = wq_fc2 + (size_t)CDIM * FFD;
    float* y             = (float*)(xnq + (size_t)MPAD * CDIM);
    short* qkvq          = (short*)(y + (size_t)ROWS * CDIM);
    float* qkvF          = (float*)(qkvq + (size_t)ROWS * QKVD);
    short* vtq           = (short*)y;
    float* h             = (float*)qkvq;
    signed char* hq      = (signed char*)(h + (size_t)ROWS * FFD);
    float* xa = out;

    // prep: partial maxima -> 1-block reduce -> quant passes (+ xnq pad-zero blocks)
    prep_a_kernel<<<NPREP, 256, 0, stream>>>(w_qkv, w_proj, w_fc1, w_fc2, x, g1, b1, partP);
    reduce_am5_kernel<<<1, 256, 0, stream>>>(partP, am);
    prep_b_kernel<<<NPREP + (MPAD - ROWS), 256, 0, stream>>>(
        w_qkv, wq_qkv, w_proj, wq_proj, w_fc1, wq_fc1, w_fc2, wq_fc2,
        x, g1, b1, xnq, am);

    // qkv (8-wave 256x128, grid 600) -> p_qkv partials
    mfma_gemm8_kernel<0><<<600, 512, 0, stream>>>(
        xnq, wq_qkv, b_qkv, qkvF, ROWS, QKVD, CDIM, QKVD / 128, am + 4, am + 0, p_qkv);
    qv_kernel<<<2048 + NBH, 256, 0, stream>>>(qkvF, qkvq, vtq, p_qkv, 600);

    // attention: amax(S) partials -> fused (inline reduces) -> p_xa partials
    attn_amax_kernel<<<dim3(4, 1, NBH), 256, 0, stream>>>(qkvq, p_qkv, 600, p_s);
    attn_fused_kernel<<<dim3(4, 1, NBH), 256, 0, stream>>>(
        qkvq, vtq, xa, p_qkv, 600, p_s, NBH * 4, p_xa);

    // proj (64x128 small-tile, grid 800, inline amA) -> p_proj
    quant_i8_kernel<<<2048, 256, 0, stream>>>(xa, xnq,
        (long long)ROWS * CDIM / 4, (long long)MPAD * CDIM / 4, p_xa, NBH * 4);
    mfma_gemmS_kernel<0><<<800, 256, 0, stream>>>(
        xnq, wq_proj, b_proj, y, ROWS, CDIM, CDIM, CDIM / 128, p_xa, NBH * 4, am + 1, p_proj);

    // residual 1: y = x + fq(y, s(p_proj)); -> p_y
    addfq_kernel<<<2048, 256, 0, stream>>>(x, nullptr, 0, y, (long long)ROWS * CDIM / 4,
                                           p_proj, 800, p_y);

    // LN2: partial amax -> reduce -> recompute-quant
    ln_kernel<0><<<ROWS, 256, 0, stream>>>(y, g2, b2, nullptr, p_y, 2048, nullptr, p_ln);
    reduce_one_kernel<<<1, 256, 0, stream>>>(p_ln, ROWS, am + 10);
    ln_kernel<1><<<ROWS, 256, 0, stream>>>(y, g2, b2, xnq, p_y, 2048, am + 10, nullptr);

    // fc1 (gelu epilogue) -> p_fc1
    mfma_gemm8_kernel<1><<<800, 512, 0, stream>>>(
        xnq, wq_fc1, b_fc1, h, ROWS, FFD, CDIM, FFD / 128, am + 10, am + 2, p_fc1);
    quant_i8_kernel<<<4096, 256, 0, stream>>>(h, hq,
        (long long)ROWS * FFD / 4, (long long)MPAD * FFD / 4, p_fc1, 800);

    // fc2 (64x128 small-tile, grid 800, inline amA) -> p_fc2
    mfma_gemmS_kernel<0><<<800, 256, 0, stream>>>(
        hq, wq_fc2, b_fc2, out, ROWS, CDIM, FFD, CDIM / 128, p_fc1, 800, am + 3, p_fc2);

    // residual 2: out = fq(y,s(p_y)) + fq(out,s(p_fc2)) -> p_r2; final fq
    addfq_kernel<<<2048, 256, 0, stream>>>(y, p_y, 2048, out, (long long)ROWS * CDIM / 4,
                                           p_fc2, 800, p_r2);
    fq_inplace_kernel<<<2048, 256, 0, stream>>>(out, (long long)ROWS * CDIM / 4, p_r2, 2048);
}

// Round 20
// 438.773 us; speedup vs baseline: 1.0263x; 1.0162x over previous
//
#include <hip/hip_runtime.h>

#define ROWS 6304      // B*N = 32*197
#define MPAD 6400      // 50 * 128
#define CDIM 1024
#define QKVD 3072
#define FFD  4096
#define NSEQ 197
#define NBH  512       // B*H
#define NPREP (3072 + ROWS)   // 9376

typedef __attribute__((ext_vector_type(8))) short bf16x8;
typedef __attribute__((ext_vector_type(4))) float f32x4;
typedef __attribute__((ext_vector_type(4))) int i32x4;

// ---------- device helpers ----------
__device__ __forceinline__ float fqv(float v, float s) {
    float q = rintf(v / s);
    q = fminf(fmaxf(q, -127.0f), 127.0f);
    return q * s;
}
__device__ __forceinline__ float gelu_f(float x) {
    const float c = 0.7978845608028654f;  // sqrt(2/pi)
    float t = tanhf(c * (x + 0.044715f * x * x * x));
    return 0.5f * x * (1.0f + t);
}
__device__ __forceinline__ short bf16_of_small_int(float q) {
    return (short)(__float_as_uint(q) >> 16);  // exact for |q| <= 255 integers
}
__device__ __forceinline__ short q_bf16(float v, float s) {
    return bf16_of_small_int(fminf(fmaxf(rintf(v / s), -127.f), 127.f));
}
// block = 256 threads (4 waves)
__device__ __forceinline__ float blockReduceSum(float v, float* sred) {
    int lane = threadIdx.x & 63, w = threadIdx.x >> 6;
    #pragma unroll
    for (int o = 32; o > 0; o >>= 1) v += __shfl_down(v, o);
    __syncthreads();
    if (lane == 0) sred[w] = v;
    __syncthreads();
    return sred[0] + sred[1] + sred[2] + sred[3];
}
__device__ __forceinline__ float blockReduceMax(float v, float* sred) {
    int lane = threadIdx.x & 63, w = threadIdx.x >> 6;
    #pragma unroll
    for (int o = 32; o > 0; o >>= 1) v = fmaxf(v, __shfl_down(v, o));
    __syncthreads();
    if (lane == 0) sred[w] = v;
    __syncthreads();
    return fmaxf(fmaxf(sred[0], sred[1]), fmaxf(sred[2], sred[3]));
}
// block = 512 threads (8 waves)
__device__ __forceinline__ float blockReduceMax8(float v, float* sred) {
    int lane = threadIdx.x & 63, w = threadIdx.x >> 6;
    #pragma unroll
    for (int o = 32; o > 0; o >>= 1) v = fmaxf(v, __shfl_down(v, o));
    __syncthreads();
    if (lane == 0) sred[w] = v;
    __syncthreads();
    float m = sred[0];
    #pragma unroll
    for (int i = 1; i < 8; i++) m = fmaxf(m, sred[i]);
    return m;
}
// inline amax over a partials array (256-thread blocks), broadcast to all threads
__device__ __forceinline__ float pmax256(const float* part, int n, float* sred) {
    float m = 0.f;
    for (int i = threadIdx.x; i < n; i += 256) m = fmaxf(m, part[i]);
    return blockReduceMax(m, sred);
}
__device__ __forceinline__ float scale_v(float amv) {
    return fmaxf(amv / 127.0f, 1e-8f);
}
__device__ __forceinline__ float scale_of(const float* am) {
    return fmaxf(am[0] / 127.0f, 1e-8f);
}

// ---------- prep_a: weight absmax (blocks 0..3071) || LN1 amax (3072..9375) ----------
__global__ __launch_bounds__(256) void prep_a_kernel(
    const float* __restrict__ w0, const float* __restrict__ w1,
    const float* __restrict__ w2, const float* __restrict__ w3,
    const float* __restrict__ x, const float* __restrict__ g1,
    const float* __restrict__ b1, float* __restrict__ part) {
    __shared__ float sred[4];
    int b = blockIdx.x, tid = threadIdx.x;
    if (b < 3072) {
        const float4* p; int base, nb;
        if (b < 768)       { p = (const float4*)w0; base = b;        nb = 768;  }
        else if (b < 1024) { p = (const float4*)w1; base = b - 768;  nb = 256;  }
        else if (b < 2048) { p = (const float4*)w2; base = b - 1024; nb = 1024; }
        else               { p = (const float4*)w3; base = b - 2048; nb = 1024; }
        float m = 0.f;
        #pragma unroll
        for (int it = 0; it < 4; it++) {
            float4 v = p[(long long)it * nb * 256 + (long long)base * 256 + tid];
            m = fmaxf(m, fmaxf(fmaxf(fabsf(v.x), fabsf(v.y)), fmaxf(fabsf(v.z), fabsf(v.w))));
        }
        m = blockReduceMax(m, sred);
        if (tid == 0) part[b] = m;
    } else {
        int row = b - 3072;
        float4 v = ((const float4*)(x + (size_t)row * CDIM))[tid];
        float sum = blockReduceSum(v.x + v.y + v.z + v.w, sred);
        float mu = sum * (1.0f / CDIM);
        float dx = v.x - mu, dy = v.y - mu, dz = v.z - mu, dw = v.w - mu;
        float var = blockReduceSum(dx * dx + dy * dy + dz * dz + dw * dw, sred) * (1.0f / CDIM);
        float rstd = rsqrtf(var + 1e-6f);
        float4 gv = ((const float4*)g1)[tid], bv = ((const float4*)b1)[tid];
        float ox = dx * rstd * gv.x + bv.x;
        float oy = dy * rstd * gv.y + bv.y;
        float oz = dz * rstd * gv.z + bv.z;
        float ow = dw * rstd * gv.w + bv.w;
        float m = fmaxf(fmaxf(fabsf(ox), fabsf(oy)), fmaxf(fabsf(oz), fabsf(ow)));
        m = blockReduceMax(m, sred);
        if (tid == 0) part[b] = m;
    }
}

// one block: collapse prep_a partials into am[0..4] (sole writer, plain stores)
__global__ __launch_bounds__(256) void reduce_am5_kernel(const float* __restrict__ part,
                                                         float* __restrict__ am) {
    __shared__ float sred[4];
    float m0 = 0.f, m1 = 0.f, m2 = 0.f, m3 = 0.f, m4 = 0.f;
    for (int i = threadIdx.x; i < NPREP; i += 256) {
        float v = part[i];
        if (i < 768) m0 = fmaxf(m0, v);
        else if (i < 1024) m1 = fmaxf(m1, v);
        else if (i < 2048) m2 = fmaxf(m2, v);
        else if (i < 3072) m3 = fmaxf(m3, v);
        else m4 = fmaxf(m4, v);
    }
    m0 = blockReduceMax(m0, sred);
    m1 = blockReduceMax(m1, sred);
    m2 = blockReduceMax(m2, sred);
    m3 = blockReduceMax(m3, sred);
    m4 = blockReduceMax(m4, sred);
    if (threadIdx.x == 0) { am[0] = m0; am[1] = m1; am[2] = m2; am[3] = m3; am[4] = m4; }
}

// one block: amDst[0] = max(part[0..n))
__global__ __launch_bounds__(256) void reduce_one_kernel(const float* __restrict__ part,
                                                         int n, float* __restrict__ amDst) {
    __shared__ float sred[4];
    float m = 0.f;
    for (int i = threadIdx.x; i < n; i += 256) m = fmaxf(m, part[i]);
    m = blockReduceMax(m, sred);
    if (threadIdx.x == 0) amDst[0] = m;
}

// ---------- prep_b: weight quant || LN1 recompute-quant || xnq pad-zero ----------
__global__ __launch_bounds__(256) void prep_b_kernel(
    const float* __restrict__ w0, signed char* __restrict__ d0,
    const float* __restrict__ w1, signed char* __restrict__ d1,
    const float* __restrict__ w2, signed char* __restrict__ d2,
    const float* __restrict__ w3, signed char* __restrict__ d3,
    const float* __restrict__ x, const float* __restrict__ g1,
    const float* __restrict__ b1, signed char* __restrict__ xnq,
    const float* __restrict__ am) {
    __shared__ float sred[4];
    int b = blockIdx.x, tid = threadIdx.x;
    if (b >= NPREP) {
        int row = ROWS + (b - NPREP);
        ((int*)xnq)[(size_t)row * (CDIM / 4) + tid] = 0;
        return;
    }
    if (b < 3072) {
        const float4* p; int* d; int base, nb; float s;
        if (b < 768)       { p = (const float4*)w0; d = (int*)d0; base = b;        nb = 768;  s = scale_of(am + 0); }
        else if (b < 1024) { p = (const float4*)w1; d = (int*)d1; base = b - 768;  nb = 256;  s = scale_of(am + 1); }
        else if (b < 2048) { p = (const float4*)w2; d = (int*)d2; base = b - 1024; nb = 1024; s = scale_of(am + 2); }
        else               { p = (const float4*)w3; d = (int*)d3; base = b - 2048; nb = 1024; s = scale_of(am + 3); }
        #pragma unroll
        for (int it = 0; it < 4; it++) {
            long long i = (long long)it * nb * 256 + (long long)base * 256 + tid;
            float4 v = p[i];
            int q0 = (int)fminf(fmaxf(rintf(v.x / s), -127.f), 127.f);
            int q1 = (int)fminf(fmaxf(rintf(v.y / s), -127.f), 127.f);
            int q2 = (int)fminf(fmaxf(rintf(v.z / s), -127.f), 127.f);
            int q3 = (int)fminf(fmaxf(rintf(v.w / s), -127.f), 127.f);
            d[i] = (q0 & 255) | ((q1 & 255) << 8) | ((q2 & 255) << 16) | (q3 << 24);
        }
    } else {
        int row = b - 3072;
        float4 v = ((const float4*)(x + (size_t)row * CDIM))[tid];
        float sum = blockReduceSum(v.x + v.y + v.z + v.w, sred);
        float mu = sum * (1.0f / CDIM);
        float dx = v.x - mu, dy = v.y - mu, dz = v.z - mu, dw = v.w - mu;
        float var = blockReduceSum(dx * dx + dy * dy + dz * dz + dw * dw, sred) * (1.0f / CDIM);
        float rstd = rsqrtf(var + 1e-6f);
        float4 gv = ((const float4*)g1)[tid], bv = ((const float4*)b1)[tid];
        float ox = dx * rstd * gv.x + bv.x;
        float oy = dy * rstd * gv.y + bv.y;
        float oz = dz * rstd * gv.z + bv.z;
        float ow = dw * rstd * gv.w + bv.w;
        float s = scale_of(am + 4);
        int q0 = (int)fminf(fmaxf(rintf(ox / s), -127.f), 127.f);
        int q1 = (int)fminf(fmaxf(rintf(oy / s), -127.f), 127.f);
        int q2 = (int)fminf(fmaxf(rintf(oz / s), -127.f), 127.f);
        int q3 = (int)fminf(fmaxf(rintf(ow / s), -127.f), 127.f);
        ((int*)xnq)[(size_t)row * (CDIM / 4) + tid] =
            (q0 & 255) | ((q1 & 255) << 8) | ((q2 & 255) << 16) | (q3 << 24);
    }
}

// ---------- LayerNorm (LN2): MODE 0 partial amax; MODE 1 recompute-quant ----------
template <int MODE>
__global__ __launch_bounds__(256) void ln_kernel(
    const float* __restrict__ x, const float* __restrict__ g,
    const float* __restrict__ bb, signed char* __restrict__ dst,
    const float* __restrict__ partIn, int nIn,
    const float* __restrict__ amQ, float* __restrict__ part) {
    __shared__ float sred[4];
    int row = blockIdx.x;
    int t = threadIdx.x;
    float sIn = scale_v(pmax256(partIn, nIn, sred));
    float4 v = ((const float4*)(x + (size_t)row * CDIM))[t];
    v.x = fqv(v.x, sIn); v.y = fqv(v.y, sIn); v.z = fqv(v.z, sIn); v.w = fqv(v.w, sIn);
    float sum = blockReduceSum(v.x + v.y + v.z + v.w, sred);
    float mu = sum * (1.0f / CDIM);
    float dx = v.x - mu, dy = v.y - mu, dz = v.z - mu, dw = v.w - mu;
    float var = blockReduceSum(dx * dx + dy * dy + dz * dz + dw * dw, sred) * (1.0f / CDIM);
    float rstd = rsqrtf(var + 1e-6f);
    float4 gv = ((const float4*)g)[t], bv = ((const float4*)bb)[t];
    float ox = dx * rstd * gv.x + bv.x;
    float oy = dy * rstd * gv.y + bv.y;
    float oz = dz * rstd * gv.z + bv.z;
    float ow = dw * rstd * gv.w + bv.w;
    if (MODE == 0) {
        float m = fmaxf(fmaxf(fabsf(ox), fabsf(oy)), fmaxf(fabsf(oz), fabsf(ow)));
        m = blockReduceMax(m, sred);
        if (t == 0) part[row] = m;
    } else {
        float s = scale_of(amQ);
        int q0 = (int)fminf(fmaxf(rintf(ox / s), -127.f), 127.f);
        int q1 = (int)fminf(fmaxf(rintf(oy / s), -127.f), 127.f);
        int q2 = (int)fminf(fmaxf(rintf(oz / s), -127.f), 127.f);
        int q3 = (int)fminf(fmaxf(rintf(ow / s), -127.f), 127.f);
        ((int*)dst)[(size_t)row * (CDIM / 4) + t] =
            (q0 & 255) | ((q1 & 255) << 8) | ((q2 & 255) << 16) | (q3 << 24);
    }
}

// final fq: s from partials
__global__ __launch_bounds__(256) void fq_inplace_kernel(float* __restrict__ buf, long long n4,
                                                         const float* __restrict__ part, int np) {
    __shared__ float sred[4];
    float s = scale_v(pmax256(part, np, sred));
    float4* b4 = (float4*)buf;
    long long stride = (long long)gridDim.x * blockDim.x;
    for (long long i = (long long)blockIdx.x * blockDim.x + threadIdx.x; i < n4; i += stride) {
        float4 v = b4[i];
        v.x = fqv(v.x, s); v.y = fqv(v.y, s); v.z = fqv(v.z, s); v.w = fqv(v.w, s);
        b4[i] = v;
    }
}

// buf[i] = FQ?(xin[i], sX) + fq(buf[i], s); scales from partials; partOut[bid] = block max
__global__ __launch_bounds__(256) void addfq_kernel(const float* __restrict__ xin,
                                                    const float* __restrict__ partX, int nX,
                                                    float* __restrict__ buf, long long n4,
                                                    const float* __restrict__ partAm, int nAm,
                                                    float* __restrict__ partOut) {
    __shared__ float sred[4];
    float s = scale_v(pmax256(partAm, nAm, sred));
    float sx = partX ? scale_v(pmax256(partX, nX, sred)) : 0.f;
    const float4* x4 = (const float4*)xin;
    float4* b4 = (float4*)buf;
    float m = 0.f;
    long long stride = (long long)gridDim.x * blockDim.x;
    for (long long i = (long long)blockIdx.x * blockDim.x + threadIdx.x; i < n4; i += stride) {
        float4 v = x4[i];
        if (partX) { v.x = fqv(v.x, sx); v.y = fqv(v.y, sx); v.z = fqv(v.z, sx); v.w = fqv(v.w, sx); }
        float4 u = b4[i];
        u.x = v.x + fqv(u.x, s);
        u.y = v.y + fqv(u.y, s);
        u.z = v.z + fqv(u.z, s);
        u.w = v.w + fqv(u.w, s);
        b4[i] = u;
        m = fmaxf(m, fmaxf(fmaxf(fabsf(u.x), fabsf(u.y)), fmaxf(fabsf(u.z), fabsf(u.w))));
    }
    m = blockReduceMax(m, sred);
    if (threadIdx.x == 0) partOut[blockIdx.x] = m;
}

// quantize to i8 levels, scale from partials, zeros for i>=n
__global__ __launch_bounds__(256) void quant_i8_kernel(const float* __restrict__ src,
                                                       signed char* __restrict__ dst,
                                                       long long n4, long long npad4,
                                                       const float* __restrict__ part, int np) {
    __shared__ float sred[4];
    float s = scale_v(pmax256(part, np, sred));
    long long stride = (long long)gridDim.x * blockDim.x;
    for (long long i = (long long)blockIdx.x * blockDim.x + threadIdx.x; i < npad4; i += stride) {
        float4 v = make_float4(0.f, 0.f, 0.f, 0.f);
        if (i < n4) v = ((const float4*)src)[i];
        int q0 = (int)fminf(fmaxf(rintf(v.x / s), -127.f), 127.f);
        int q1 = (int)fminf(fmaxf(rintf(v.y / s), -127.f), 127.f);
        int q2 = (int)fminf(fmaxf(rintf(v.z / s), -127.f), 127.f);
        int q3 = (int)fminf(fmaxf(rintf(v.w / s), -127.f), 127.f);
        ((int*)dst)[i] = (q0 & 255) | ((q1 & 255) << 8) | ((q2 & 255) << 16) | (q3 << 24);
    }
}

// ---------- qv: blocks [0,2048) quantize Q,K cols -> bf16 levels; [2048,2560) V-transpose ----------
__global__ __launch_bounds__(256) void qv_kernel(const float* __restrict__ qkvF,
                                                 short* __restrict__ qkvq,
                                                 short* __restrict__ vtq,
                                                 const float* __restrict__ part5, int np5) {
    __shared__ short T[NSEQ * 65];
    __shared__ float sred[4];
    float s = scale_v(pmax256(part5, np5, sred));
    int b = blockIdx.x, tid = threadIdx.x;
    if (b < 2048) {
        const long long n4 = (long long)ROWS * 512;
        for (long long i = (long long)b * 256 + tid; i < n4; i += (long long)2048 * 256) {
            long long row = i >> 9;
            int c4 = (int)(i & 511);
            float4 v = ((const float4*)(qkvF + row * QKVD))[c4];
            short4 o;
            o.x = q_bf16(v.x, s); o.y = q_bf16(v.y, s);
            o.z = q_bf16(v.z, s); o.w = q_bf16(v.w, s);
            ((short4*)(qkvq + row * QKVD))[c4] = o;
        }
    } else {
        int z = b - 2048, bb = z >> 4, hh = z & 15;
        const float* vb = qkvF + (size_t)bb * NSEQ * QKVD + 2048 + hh * 64;
        for (int c = tid; c < NSEQ * 16; c += 256) {
            int m = c >> 4, p = c & 15;
            float4 v = ((const float4*)(vb + (size_t)m * QKVD))[p];
            T[m * 65 + p * 4 + 0] = q_bf16(v.x, s);
            T[m * 65 + p * 4 + 1] = q_bf16(v.y, s);
            T[m * 65 + p * 4 + 2] = q_bf16(v.z, s);
            T[m * 65 + p * 4 + 3] = q_bf16(v.w, s);
        }
        __syncthreads();
        short* obase = vtq + (size_t)z * 64 * 256;
        for (int c = tid; c < 64 * 32; c += 256) {
            int d = c >> 5, sl = c & 31;
            int sp = sl ^ (d & 7);
            bf16x8 o;
            #pragma unroll
            for (int jj = 0; jj < 8; jj++) {
                int m = sl * 8 + jj;
                o[jj] = (m < NSEQ) ? T[m * 65 + d] : (short)0;
            }
            *(bf16x8*)&obase[d * 256 + sp * 8] = o;
        }
    }
}

#define GLL(gp, lp) __builtin_amdgcn_global_load_lds( \
    (const __attribute__((address_space(1))) void*)(gp), \
    (__attribute__((address_space(3))) void*)(lp), 16, 0, 0)

// ---------- attention pass 1: amax(S) only, s5 from partials ----------
__global__ __launch_bounds__(256, 2) void attn_amax_kernel(
    const short* __restrict__ qkvq,
    const float* __restrict__ part5, int np5, float* __restrict__ part) {
    __shared__ __align__(16) short Qs[256 * 32];
    __shared__ __align__(16) short Ks[64 * 32];
    __shared__ float sred[4];
    const int tid = threadIdx.x, lane = tid & 63, wave = tid >> 6;
    const int z = blockIdx.z, b = z >> 4, hh = z & 15;
    const int n0 = blockIdx.x * 64;
    const float s5 = scale_v(pmax256(part5, np5, sred));
    const float sc = s5 * s5 * 0.125f;
    const short* qbase = qkvq + (size_t)b * NSEQ * QKVD + hh * 64;
    const short* kbase = qbase + 1024;

    f32x4 acc[4][4] = {};
    const int piece = (tid & 3) * 8;
    const short* srcA[4];
    #pragma unroll
    for (int i = 0; i < 4; i++) {
        int row = i * 64 + (tid >> 2);
        srcA[i] = qbase + (size_t)min(row, NSEQ - 1) * QKVD + piece;
    }
    const short* srcB = kbase + (size_t)min(n0 + (tid >> 2), NSEQ - 1) * QKVD + piece;
    const int lr = lane & 15;
    const int koff = (lane >> 4) * 8;

    for (int k0 = 0; k0 < 64; k0 += 32) {
        __syncthreads();
        #pragma unroll
        for (int i = 0; i < 4; i++) GLL(srcA[i] + k0, Qs + i * 2048 + wave * 512);
        GLL(srcB + k0, Ks + wave * 512);
        __syncthreads();

        bf16x8 a[4], bfr[4];
        #pragma unroll
        for (int i = 0; i < 4; i++)
            a[i] = *(const bf16x8*)&Qs[(wave * 64 + i * 16 + lr) * 32 + koff];
        #pragma unroll
        for (int j = 0; j < 4; j++)
            bfr[j] = *(const bf16x8*)&Ks[(j * 16 + lr) * 32 + koff];
        #pragma unroll
        for (int i = 0; i < 4; i++)
            #pragma unroll
            for (int j = 0; j < 4; j++)
                acc[i][j] = __builtin_amdgcn_mfma_f32_16x16x32_bf16(a[i], bfr[j], acc[i][j], 0, 0, 0);
    }

    const int cr = (lane >> 4) * 4;
    const int cc = lane & 15;
    float mloc = 0.f;
    #pragma unroll
    for (int i = 0; i < 4; i++) {
        #pragma unroll
        for (int j = 0; j < 4; j++) {
            int gn = n0 + j * 16 + cc;
            #pragma unroll
            for (int r = 0; r < 4; r++) {
                int gm = wave * 64 + i * 16 + cr + r;
                if (gm < NSEQ && gn < NSEQ)
                    mloc = fmaxf(mloc, fabsf(acc[i][j][r] * sc));
            }
        }
    }
    mloc = blockReduceMax(mloc, sred);
    if (tid == 0) part[z * 4 + blockIdx.x] = mloc;
}

// ---------- attention pass 2: fused QK^T -> fq -> softmax -> uint8 grid -> PV ----------
__global__ __launch_bounds__(256, 2) void attn_fused_kernel(
    const short* __restrict__ qkvq, const short* __restrict__ vtq,
    float* __restrict__ xa,
    const float* __restrict__ part5, int np5,
    const float* __restrict__ part6, int np6,
    float* __restrict__ part) {
    __shared__ __align__(16) short Qs[64 * 64];
    __shared__ __align__(16) short UN[64 * 256];
    __shared__ __align__(16) short Vs[64 * 256];
    __shared__ float sred[4];
    const int tid = threadIdx.x, lane = tid & 63, wave = tid >> 6;
    const int z = blockIdx.z, b = z >> 4, hh = z & 15, rb = blockIdx.x;
    const float s5 = scale_v(pmax256(part5, np5, sred));
    const float s6 = scale_v(pmax256(part6, np6, sred));
    const float sc = s5 * s5 * 0.125f;
    const short* qbase = qkvq + (size_t)b * NSEQ * QKVD + hh * 64;
    const short* kbase = qbase + 1024;

    #pragma unroll
    for (int i = 0; i < 2; i++) {
        int c = tid + 256 * i;
        int r = c >> 3, sl = c & 7;
        int gr = min(rb * 64 + r, NSEQ - 1);
        GLL(qbase + (size_t)gr * QKVD + ((sl ^ (r & 7)) * 8), Qs + c * 8);
    }
    #pragma unroll
    for (int i = 0; i < 7; i++) {
        int c = tid + 256 * i;
        int n = c >> 3, sl = c & 7;
        int gn = min(n, NSEQ - 1);
        GLL(kbase + (size_t)gn * QKVD + ((sl ^ (n & 7)) * 8), UN + c * 8);
    }
    {
        const short* vsrc = vtq + (size_t)z * 64 * 256;
        #pragma unroll
        for (int i = 0; i < 8; i++) {
            int c = tid + 256 * i;
            GLL(vsrc + c * 8, Vs + c * 8);
        }
    }
    __syncthreads();

    const int lr = lane & 15, klane = lane >> 4;
    f32x4 acc[14];
    #pragma unroll
    for (int cb = 0; cb < 14; cb++) acc[cb] = (f32x4){0.f, 0.f, 0.f, 0.f};
    #pragma unroll
    for (int ks = 0; ks < 2; ks++) {
        int r = wave * 16 + lr;
        bf16x8 aq = *(const bf16x8*)&Qs[r * 64 + (((ks * 4 + klane) ^ (r & 7)) * 8)];
        #pragma unroll
        for (int cb = 0; cb < 14; cb++) {
            int n = cb * 16 + lr;
            bf16x8 bk = *(const bf16x8*)&UN[n * 64 + (((ks * 4 + klane) ^ (n & 7)) * 8)];
            acc[cb] = __builtin_amdgcn_mfma_f32_16x16x32_bf16(aq, bk, acc[cb], 0, 0, 0);
        }
    }
    __syncthreads();

    #pragma unroll
    for (int reg = 0; reg < 4; reg++) {
        int rloc = wave * 16 + klane * 4 + reg;
        float v[14], mx = -3.0e38f;
        #pragma unroll
        for (int cb = 0; cb < 14; cb++) {
            int col = cb * 16 + lr;
            float q = fqv(acc[cb][reg] * sc, s6);
            v[cb] = (col < NSEQ) ? q : -3.0e38f;
            mx = fmaxf(mx, v[cb]);
        }
        #pragma unroll
        for (int o = 8; o > 0; o >>= 1) mx = fmaxf(mx, __shfl_xor(mx, o));
        float e[14], sum = 0.f;
        #pragma unroll
        for (int cb = 0; cb < 14; cb++) {
            int col = cb * 16 + lr;
            e[cb] = (col < NSEQ) ? expf(v[cb] - mx) : 0.f;
            sum += e[cb];
        }
        #pragma unroll
        for (int o = 8; o > 0; o >>= 1) sum += __shfl_xor(sum, o);
        #pragma unroll
        for (int cb = 0; cb < 14; cb++) {
            int col = cb * 16 + lr;
            float plvl = (col < NSEQ) ? rintf(e[cb] / sum * 255.0f) : 0.f;
            UN[rloc * 256 + (((col >> 3) ^ (rloc & 7)) * 8) + (col & 7)] = bf16_of_small_int(plvl);
        }
    }
    __syncthreads();

    f32x4 acc2[4];
    #pragma unroll
    for (int j = 0; j < 4; j++) acc2[j] = (f32x4){0.f, 0.f, 0.f, 0.f};
    #pragma unroll
    for (int ks = 0; ks < 7; ks++) {
        int r = wave * 16 + lr;
        bf16x8 ap = *(const bf16x8*)&UN[r * 256 + (((ks * 4 + klane) ^ (r & 7)) * 8)];
        #pragma unroll
        for (int j = 0; j < 4; j++) {
            int d = j * 16 + lr;
            bf16x8 bv = *(const bf16x8*)&Vs[d * 256 + (((ks * 4 + klane) ^ (d & 7)) * 8)];
            acc2[j] = __builtin_amdgcn_mfma_f32_16x16x32_bf16(ap, bv, acc2[j], 0, 0, 0);
        }
    }
    const float sc2 = s5 * (1.0f / 255.0f);
    float mloc = 0.f;
    #pragma unroll
    for (int j = 0; j < 4; j++) {
        int d = j * 16 + lr;
        #pragma unroll
        for (int r = 0; r < 4; r++) {
            int grow = rb * 64 + wave * 16 + klane * 4 + r;
            if (grow < NSEQ) {
                float vv = acc2[j][r] * sc2;
                xa[((size_t)b * NSEQ + grow) * CDIM + hh * 64 + d] = vv;
                mloc = fmaxf(mloc, fabsf(vv));
            }
        }
    }
    mloc = blockReduceMax(mloc, sred);
    if (tid == 0) part[z * 4 + rb] = mloc;
}

// ---------- i8 MFMA GEMM, 4-wave 64x128 "small" (fc2, proj): r19 proven ----------
template <int EPI>
__global__ __launch_bounds__(256, 4) void mfma_gemmS_kernel(
    const signed char* __restrict__ Aq, const signed char* __restrict__ Bq,
    const float* __restrict__ bias, float* __restrict__ C,
    int M, int N, int K, int NBX,
    const float* __restrict__ partA, int nA,
    const float* __restrict__ amB, float* __restrict__ partOut) {
    __shared__ __align__(16) signed char As[2][64 * 64];
    __shared__ __align__(16) signed char Bs[2][128 * 64];
    __shared__ float sred[4];
    const int tid = threadIdx.x;
    const int lane = tid & 63;
    const int wave = tid >> 6;
    const int wg = (blockIdx.x & 7) * ((int)gridDim.x >> 3) + ((int)blockIdx.x >> 3);
    const int n0 = (wg % NBX) * 128;
    const int m0 = (wg / NBX) * 64;
    const int wm = (wave >> 1) * 32;
    const int wn = (wave & 1) * 64;

    i32x4 acc[2][4] = {};

    const signed char* gA;
    {
        int row = tid >> 2;
        int gsl = ((tid & 3) ^ (row & 3)) * 16;
        gA = Aq + (size_t)(m0 + row) * K + gsl;
    }
    const signed char* gB[2];
    #pragma unroll
    for (int i = 0; i < 2; i++) {
        int s = tid + 256 * i;
        int row = s >> 2;
        int gsl = ((s & 3) ^ (row & 3)) * 16;
        gB[i] = Bq + (size_t)(n0 + row) * K + gsl;
    }
    const int lr = lane & 15;
    const int klane = lane >> 4;
    int offA[2], offB[4];
    #pragma unroll
    for (int i = 0; i < 2; i++) {
        int ra = wm + i * 16 + lr;
        offA[i] = ra * 64 + ((klane ^ (ra & 3)) * 16);
    }
    #pragma unroll
    for (int j = 0; j < 4; j++) {
        int rb = wn + j * 16 + lr;
        offB[j] = rb * 64 + ((klane ^ (rb & 3)) * 16);
    }

#define STAGES(buf, kk) do { \
    GLL(gA + (kk),    &As[buf][wave * 1024]); \
    GLL(gB[0] + (kk), &Bs[buf][wave * 1024]); \
    GLL(gB[1] + (kk), &Bs[buf][wave * 1024 + 4096]); \
} while (0)

#define COMPUTES(buf) do { \
    i32x4 a[2], b[4]; \
    _Pragma("unroll") \
    for (int i = 0; i < 2; i++) a[i] = *(const i32x4*)&As[buf][offA[i]]; \
    _Pragma("unroll") \
    for (int j = 0; j < 4; j++) b[j] = *(const i32x4*)&Bs[buf][offB[j]]; \
    _Pragma("unroll") \
    for (int i = 0; i < 2; i++) \
        _Pragma("unroll") \
        for (int j = 0; j < 4; j++) \
            acc[i][j] = __builtin_amdgcn_mfma_i32_16x16x64_i8(a[i], b[j], acc[i][j], 0, 0, 0); \
} while (0)

    asm volatile("s_waitcnt vmcnt(0)" ::: "memory");
    STAGES(0, 0);
    STAGES(1, 64);
    const int NK = K >> 6;
    for (int t = 0; t < NK; ++t) {
        if (t + 1 < NK) { asm volatile("s_waitcnt vmcnt(3)" ::: "memory"); }
        else            { asm volatile("s_waitcnt vmcnt(0)" ::: "memory"); }
        __builtin_amdgcn_sched_barrier(0);
        __builtin_amdgcn_s_barrier();
        COMPUTES(t & 1);
        __builtin_amdgcn_s_barrier();
        if (t + 2 < NK) STAGES(t & 1, (t + 2) << 6);
    }
    __builtin_amdgcn_sched_barrier(0);
#undef STAGES
#undef COMPUTES

    const float sAB = scale_v(pmax256(partA, nA, sred)) * scale_of(amB);
    const int cr = (lane >> 4) * 4;
    const int cc = lane & 15;
    float mloc = 0.f;
    #pragma unroll
    for (int i = 0; i < 2; i++) {
        #pragma unroll
        for (int j = 0; j < 4; j++) {
            int gn = n0 + wn + j * 16 + cc;
            float bv = bias[gn];
            #pragma unroll
            for (int r = 0; r < 4; r++) {
                int gm = m0 + wm + i * 16 + cr + r;
                if (gm >= M) continue;
                float v = (float)acc[i][j][r] * sAB + bv;
                if (EPI == 1) v = gelu_f(v);
                C[(size_t)gm * N + gn] = v;
                mloc = fmaxf(mloc, fabsf(v));
            }
        }
    }
    mloc = blockReduceMax(mloc, sred);
    if (tid == 0) partOut[blockIdx.x] = mloc;
}

// ---------- i8 MFMA GEMM, 8-wave 256x128 (qkv, fc1): template phase order ----------
// Per tile: wait vmcnt(3); barrier; ds_read x8; lgkm(0); barrier; STAGE(t+2);
// setprio(1); 16 MFMA; setprio(0).  STAGE precedes compute -> ~2 phases of
// latency cover; explicit load/compute phase split gives setprio leverage.
template <int EPI>
__global__ __launch_bounds__(512, 4) void mfma_gemm8_kernel(
    const signed char* __restrict__ Aq, const signed char* __restrict__ Bq,
    const float* __restrict__ bias, float* __restrict__ C,
    int M, int N, int K, int NBX,
    const float* __restrict__ amA, const float* __restrict__ amB,
    float* __restrict__ partOut) {
    __shared__ __align__(16) signed char As[2][256 * 64];
    __shared__ __align__(16) signed char Bs[2][128 * 64];
    __shared__ float sred[8];
    const int tid = threadIdx.x;
    const int lane = tid & 63;
    const int wave = tid >> 6;
    const int wg = (blockIdx.x & 7) * ((int)gridDim.x >> 3) + ((int)blockIdx.x >> 3);
    const int n0 = (wg % NBX) * 128;
    const int m0 = (wg / NBX) * 256;
    const int wm = (wave >> 1) * 64;
    const int wn = (wave & 1) * 64;
    const float sAB = scale_of(amA) * scale_of(amB);

    i32x4 acc[4][4] = {};

    const signed char* gA[2];
    #pragma unroll
    for (int i = 0; i < 2; i++) {
        int s = tid + 512 * i;
        int row = s >> 2;
        int gsl = ((s & 3) ^ (row & 3)) * 16;
        gA[i] = Aq + (size_t)(m0 + row) * K + gsl;
    }
    const signed char* gB;
    {
        int row = tid >> 2;
        int gsl = ((tid & 3) ^ (row & 3)) * 16;
        gB = Bq + (size_t)(n0 + row) * K + gsl;
    }
    const int lr = lane & 15;
    const int klane = lane >> 4;
    int offA[4], offB[4];
    #pragma unroll
    for (int i = 0; i < 4; i++) {
        int ra = wm + i * 16 + lr;
        int rb = wn + i * 16 + lr;
        offA[i] = ra * 64 + ((klane ^ (ra & 3)) * 16);
        offB[i] = rb * 64 + ((klane ^ (rb & 3)) * 16);
    }

#define STAGE(buf, kk) do { \
    GLL(gA[0] + (kk), &As[buf][wave * 1024]); \
    GLL(gA[1] + (kk), &As[buf][wave * 1024 + 8192]); \
    GLL(gB + (kk),    &Bs[buf][wave * 1024]); \
} while (0)

    asm volatile("s_waitcnt vmcnt(0)" ::: "memory");
    STAGE(0, 0);
    STAGE(1, 64);
    const int NK = K >> 6;
    for (int t = 0; t < NK; ++t) {
        // phase L: wait tile t's loads, load fragments to registers
        if (t + 1 < NK) { asm volatile("s_waitcnt vmcnt(3)" ::: "memory"); }
        else            { asm volatile("s_waitcnt vmcnt(0)" ::: "memory"); }
        __builtin_amdgcn_sched_barrier(0);
        __builtin_amdgcn_s_barrier();           // buf t ready for all waves
        i32x4 a[4], b[4];
        #pragma unroll
        for (int i = 0; i < 4; i++) {
            a[i] = *(const i32x4*)&As[t & 1][offA[i]];
            b[i] = *(const i32x4*)&Bs[t & 1][offB[i]];
        }
        asm volatile("s_waitcnt lgkmcnt(0)" ::: "memory");
        __builtin_amdgcn_sched_barrier(0);
        __builtin_amdgcn_s_barrier();           // all waves' reads in registers
        // phase S: issue next-next tile's loads (buf t is now dead)
        if (t + 2 < NK) STAGE(t & 1, (t + 2) << 6);
        // phase C: MFMA cluster at raised priority
        __builtin_amdgcn_s_setprio(1);
        #pragma unroll
        for (int i = 0; i < 4; i++)
            #pragma unroll
            for (int j = 0; j < 4; j++)
                acc[i][j] = __builtin_amdgcn_mfma_i32_16x16x64_i8(a[i], b[j], acc[i][j], 0, 0, 0);
        __builtin_amdgcn_s_setprio(0);
    }
    __builtin_amdgcn_sched_barrier(0);
#undef STAGE

    const int cr = (lane >> 4) * 4;
    const int cc = lane & 15;
    float mloc = 0.f;
    #pragma unroll
    for (int i = 0; i < 4; i++) {
        #pragma unroll
        for (int j = 0; j < 4; j++) {
            int gn = n0 + wn + j * 16 + cc;
            float bv = bias[gn];
            #pragma unroll
            for (int r = 0; r < 4; r++) {
                int gm = m0 + wm + i * 16 + cr + r;
                if (gm >= M) continue;
                float v = (float)acc[i][j][r] * sAB + bv;
                if (EPI == 1) v = gelu_f(v);
                C[(size_t)gm * N + gn] = v;
                mloc = fmaxf(mloc, fabsf(v));
            }
        }
    }
    mloc = blockReduceMax8(mloc, sred);
    if (tid == 0) partOut[blockIdx.x] = mloc;
}

// ---------- launcher ----------
extern "C" void kernel_launch(void* const* d_in, const int* in_sizes, int n_in,
                              void* d_out, int out_size, void* d_ws, size_t ws_size,
                              hipStream_t stream) {
    (void)in_sizes; (void)n_in; (void)out_size; (void)ws_size;
    const float* x      = (const float*)d_in[0];
    const float* g1     = (const float*)d_in[1];
    const float* b1     = (const float*)d_in[2];
    const float* w_qkv  = (const float*)d_in[3];
    const float* b_qkv  = (const float*)d_in[4];
    const float* w_proj = (const float*)d_in[5];
    const float* b_proj = (const float*)d_in[6];
    const float* g2     = (const float*)d_in[7];
    const float* b2     = (const float*)d_in[8];
    const float* w_fc1  = (const float*)d_in[9];
    const float* b_fc1  = (const float*)d_in[10];
    const float* w_fc2  = (const float*)d_in[11];
    const float* b_fc2  = (const float*)d_in[12];
    float* out = (float*)d_out;
    float* ws  = (float*)d_ws;

    float* am       = ws;                  // 64 (slots 0..4 by reduce_am5, 10 by reduce_one)
    float* partP    = ws + 64;             // 16384 (prep)
    float* p_qkv    = partP + 16384;       // 1024 (600 used)
    float* p_s      = p_qkv + 1024;        // 2048
    float* p_xa     = p_s + 2048;          // 2048
    float* p_proj   = p_xa + 2048;         // 1024 (800 used)
    float* p_y      = p_proj + 1024;       // 2048
    float* p_ln     = p_y + 2048;          // 6400 (ROWS)
    float* p_fc1    = p_ln + 6400;         // 1024 (800)
    float* p_fc2    = p_fc1 + 1024;        // 1024 (800)
    float* p_r2     = p_fc2 + 1024;        // 2048
    signed char* wq_qkv  = (signed char*)(p_r2 + 2048);
    signed char* wq_proj = wq_qkv + (size_t)QKVD * CDIM;
    signed char* wq_fc1  = wq_proj + (size_t)CDIM * CDIM;
    signed char* wq_fc2  = wq_fc1 + (size_t)FFD * CDIM;
    signed char* xnq     = wq_fc2 + (size_t)CDIM * FFD;
    float* y             = (float*)(xnq + (size_t)MPAD * CDIM);
    short* qkvq          = (short*)(y + (size_t)ROWS * CDIM);
    float* qkvF          = (float*)(qkvq + (size_t)ROWS * QKVD);
    short* vtq           = (short*)y;
    float* h             = (float*)qkvq;
    signed char* hq      = (signed char*)(h + (size_t)ROWS * FFD);
    float* xa = out;

    // prep: partial maxima -> 1-block reduce -> quant passes (+ xnq pad-zero blocks)
    prep_a_kernel<<<NPREP, 256, 0, stream>>>(w_qkv, w_proj, w_fc1, w_fc2, x, g1, b1, partP);
    reduce_am5_kernel<<<1, 256, 0, stream>>>(partP, am);
    prep_b_kernel<<<NPREP + (MPAD - ROWS), 256, 0, stream>>>(
        w_qkv, wq_qkv, w_proj, wq_proj, w_fc1, wq_fc1, w_fc2, wq_fc2,
        x, g1, b1, xnq, am);

    // qkv (8-wave 256x128, grid 600) -> p_qkv partials
    mfma_gemm8_kernel<0><<<600, 512, 0, stream>>>(
        xnq, wq_qkv, b_qkv, qkvF, ROWS, QKVD, CDIM, QKVD / 128, am + 4, am + 0, p_qkv);
    qv_kernel<<<2048 + NBH, 256, 0, stream>>>(qkvF, qkvq, vtq, p_qkv, 600);

    // attention: amax(S) partials -> fused (inline reduces) -> p_xa partials
    attn_amax_kernel<<<dim3(4, 1, NBH), 256, 0, stream>>>(qkvq, p_qkv, 600, p_s);
    attn_fused_kernel<<<dim3(4, 1, NBH), 256, 0, stream>>>(
        qkvq, vtq, xa, p_qkv, 600, p_s, NBH * 4, p_xa);

    // proj (64x128 small-tile, grid 800, inline amA) -> p_proj
    quant_i8_kernel<<<2048, 256, 0, stream>>>(xa, xnq,
        (long long)ROWS * CDIM / 4, (long long)MPAD * CDIM / 4, p_xa, NBH * 4);
    mfma_gemmS_kernel<0><<<800, 256, 0, stream>>>(
        xnq, wq_proj, b_proj, y, ROWS, CDIM, CDIM, CDIM / 128, p_xa, NBH * 4, am + 1, p_proj);

    // residual 1: y = x + fq(y, s(p_proj)); -> p_y
    addfq_kernel<<<2048, 256, 0, stream>>>(x, nullptr, 0, y, (long long)ROWS * CDIM / 4,
                                           p_proj, 800, p_y);

    // LN2: partial amax -> reduce -> recompute-quant
    ln_kernel<0><<<ROWS, 256, 0, stream>>>(y, g2, b2, nullptr, p_y, 2048, nullptr, p_ln);
    reduce_one_kernel<<<1, 256, 0, stream>>>(p_ln, ROWS, am + 10);
    ln_kernel<1><<<ROWS, 256, 0, stream>>>(y, g2, b2, xnq, p_y, 2048, am + 10, nullptr);

    // fc1 (gelu epilogue) -> p_fc1
    mfma_gemm8_kernel<1><<<800, 512, 0, stream>>>(
        xnq, wq_fc1, b_fc1, h, ROWS, FFD, CDIM, FFD / 128, am + 10, am + 2, p_fc1);
    quant_i8_kernel<<<4096, 256, 0, stream>>>(h, hq,
        (long long)ROWS * FFD / 4, (long long)MPAD * FFD / 4, p_fc1, 800);

    // fc2 (64x128 small-tile, grid 800, inline amA) -> p_fc2
    mfma_gemmS_kernel<0><<<800, 256, 0, stream>>>(
        hq, wq_fc2, b_fc2, out, ROWS, CDIM, FFD, CDIM / 128, p_fc1, 800, am + 3, p_fc2);

    // residual 2: out = fq(y,s(p_y)) + fq(out,s(p_fc2)) -> p_r2; final fq
    addfq_kernel<<<2048, 256, 0, stream>>>(y, p_y, 2048, out, (long long)ROWS * CDIM / 4,
                                           p_fc2, 800, p_r2);
    fq_inplace_kernel<<<2048, 256, 0, stream>>>(out, (long long)ROWS * CDIM / 4, p_r2, 2048);
}